// Round 3
// baseline (945.257 us; speedup 1.0000x reference)
//
#include <hip/hip_runtime.h>
#include <hip/hip_bf16.h>

#define NNODES 20000
#define NEDGES 640000
#define NB 50
#define NF 128
#define NBLK_SCAN 79   // ceil(20000/256)

typedef unsigned int uint_t;
typedef unsigned short ushort_t;

typedef __bf16 bf16x8 __attribute__((ext_vector_type(8)));
typedef float f32x4 __attribute__((ext_vector_type(4)));

// fast shifted softplus: hardware v_exp_f32 / v_log_f32
__device__ __forceinline__ float ssp_f(float x) {
    float t = __expf(-fabsf(x));
    return fmaxf(x, 0.0f) + __logf(1.0f + t) - 0.6931471805599453f;
}

// ---------------- zero hist + cnt + work counter ----------------
__global__ __launch_bounds__(256) void k_zero_small(int* __restrict__ p, int n) {
    int i = blockIdx.x * 256 + threadIdx.x;
    if (i < n) p[i] = 0;
}

// ---------------- histogram of dst ----------------
__global__ __launch_bounds__(256) void k_hist(const int* __restrict__ dst, int* __restrict__ hist) {
    int i = blockIdx.x * 256 + threadIdx.x;
    if (i < NEDGES) atomicAdd(&hist[dst[i]], 1);
}

// ---------------- hierarchical exclusive scan: blocksums ----------------
__global__ __launch_bounds__(256) void k_bsum(const int* __restrict__ hist, int* __restrict__ bsum) {
    __shared__ int ws[4];
    int i = blockIdx.x * 256 + threadIdx.x;
    int v = (i < NNODES) ? hist[i] : 0;
    #pragma unroll
    for (int s = 1; s < 64; s <<= 1) v += __shfl_xor(v, s, 64);
    if ((threadIdx.x & 63) == 0) ws[threadIdx.x >> 6] = v;
    __syncthreads();
    if (threadIdx.x == 0) bsum[blockIdx.x] = ws[0] + ws[1] + ws[2] + ws[3];
}

__global__ __launch_bounds__(64) void k_scan_b(const int* __restrict__ bsum, int* __restrict__ bbase) {
    if (threadIdx.x == 0) {
        int acc = 0;
        for (int b = 0; b < NBLK_SCAN; ++b) { bbase[b] = acc; acc += bsum[b]; }
    }
}

__global__ __launch_bounds__(256) void k_off(const int* __restrict__ hist, const int* __restrict__ bbase,
                                             int* __restrict__ off) {
    __shared__ int buf[256];
    int i = blockIdx.x * 256 + threadIdx.x;
    int v = (i < NNODES) ? hist[i] : 0;
    buf[threadIdx.x] = v;
    __syncthreads();
    #pragma unroll
    for (int s = 1; s < 256; s <<= 1) {
        int t = (threadIdx.x >= (unsigned)s) ? buf[threadIdx.x - s] : 0;
        __syncthreads();
        buf[threadIdx.x] += t;
        __syncthreads();
    }
    if (i < NNODES) off[i] = bbase[blockIdx.x] + buf[threadIdx.x] - v;
    if (i == NNODES) off[NNODES] = NEDGES;
}

// ---------------- scatter: dst-grouped perm + pre-gathered src + cutoff ----------------
__global__ __launch_bounds__(256) void k_scatter(const int* __restrict__ src, const int* __restrict__ dst,
                                                 const float* __restrict__ ew,
                                                 const int* __restrict__ off, int* __restrict__ cnt,
                                                 int* __restrict__ perm, int* __restrict__ srcs,
                                                 float* __restrict__ Cs) {
    int i = blockIdx.x * 256 + threadIdx.x;
    if (i < NEDGES) {
        int d = dst[i];
        int pos = off[d] + atomicAdd(&cnt[d], 1);
        perm[pos] = i;
        srcs[pos] = src[i];
        Cs[pos]   = 0.5f * (__cosf(ew[i] * 0.31415926535897931f) + 1.0f);
    }
}

// ---------------- precompute w1 B-fragment table (16 KB, L1-resident in k_edge_csr) ----------------
__global__ __launch_bounds__(256) void k_prep_w1(const float* __restrict__ w1, __bf16* __restrict__ w1fg) {
    int idx = blockIdx.x * 256 + threadIdx.x;   // 0..1023 frag-lane entries
    if (idx < 16 * 64) {
        int fr = idx >> 6, l = idx & 63;
        int ntg = fr >> 1, kc = fr & 1;
        int n = ntg * 16 + (l & 15), kb = kc * 32 + (l >> 4) * 8;
        __bf16* d = &w1fg[idx * 8];
        #pragma unroll
        for (int j = 0; j < 8; ++j) {
            int k = kb + j;
            d[j] = (__bf16)((k < NB) ? w1[k * NF + n] : 0.0f);
        }
    }
}

// ---------------- node GEMM: Y = X @ W  (MFMA, 64-row tile) ----------------
__global__ __launch_bounds__(256) void k_node1(const float* __restrict__ X,
                                               const float* __restrict__ W,
                                               float* __restrict__ Y, int nrows)
{
    __shared__ alignas(16) __bf16 sx[64 * 136];
    const int tid  = threadIdx.x;
    const int wv   = tid >> 6, lane = tid & 63;
    const int col  = lane & 15, quad = lane >> 4;

    bf16x8 wf[2][4];
    #pragma unroll
    for (int nt = 0; nt < 2; ++nt) {
        int n = wv * 32 + nt * 16 + col;
        #pragma unroll
        for (int kc = 0; kc < 4; ++kc)
            #pragma unroll
            for (int j = 0; j < 8; ++j)
                wf[nt][kc][j] = (__bf16)W[(kc * 32 + quad * 8 + j) * NF + n];
    }

    const int rbase = blockIdx.x * 64;
    for (int i = tid; i < 64 * 64; i += 256) {
        int r = i >> 6, c = i & 63;
        int gr = rbase + r;
        float2 v = (gr < nrows) ? *reinterpret_cast<const float2*>(&X[(size_t)gr * NF + 2 * c])
                                : make_float2(0.f, 0.f);
        sx[r * 136 + 2 * c]     = (__bf16)v.x;
        sx[r * 136 + 2 * c + 1] = (__bf16)v.y;
    }
    __syncthreads();

    f32x4 acc[4][2] = {};
    #pragma unroll
    for (int kc = 0; kc < 4; ++kc) {
        bf16x8 af[4];
        #pragma unroll
        for (int mt = 0; mt < 4; ++mt)
            af[mt] = *reinterpret_cast<const bf16x8*>(&sx[(mt * 16 + col) * 136 + kc * 32 + quad * 8]);
        #pragma unroll
        for (int mt = 0; mt < 4; ++mt)
            #pragma unroll
            for (int nt = 0; nt < 2; ++nt)
                acc[mt][nt] = __builtin_amdgcn_mfma_f32_16x16x32_bf16(af[mt], wf[nt][kc], acc[mt][nt], 0, 0, 0);
    }
    #pragma unroll
    for (int mt = 0; mt < 4; ++mt)
        #pragma unroll
        for (int nt = 0; nt < 2; ++nt)
            #pragma unroll
            for (int r = 0; r < 4; ++r) {
                int row = rbase + mt * 16 + quad * 4 + r;
                if (row < nrows) Y[(size_t)row * NF + wv * 32 + nt * 16 + col] = acc[mt][nt][r];
            }
}

// ---------------- fused tail: out = ssp(X @ W1 + b1) @ W2 + b2 ----------------
__global__ __launch_bounds__(256) void k_tail(const float* __restrict__ X,
                                              const float* __restrict__ W1, const float* __restrict__ B1,
                                              const float* __restrict__ W2, const float* __restrict__ B2,
                                              float* __restrict__ Y, int nrows)
{
    __shared__ alignas(16) __bf16 sx[64 * 136];
    __shared__ alignas(16) __bf16 st[64 * 136];
    const int tid  = threadIdx.x;
    const int wv   = tid >> 6, lane = tid & 63;
    const int col  = lane & 15, quad = lane >> 4;

    bf16x8 wf1[2][4], wf2[2][4];
    float rb1[2], rb2[2];
    #pragma unroll
    for (int nt = 0; nt < 2; ++nt) {
        int n = wv * 32 + nt * 16 + col;
        rb1[nt] = B1[n]; rb2[nt] = B2[n];
        #pragma unroll
        for (int kc = 0; kc < 4; ++kc)
            #pragma unroll
            for (int j = 0; j < 8; ++j) {
                int k = kc * 32 + quad * 8 + j;
                wf1[nt][kc][j] = (__bf16)W1[k * NF + n];
                wf2[nt][kc][j] = (__bf16)W2[k * NF + n];
            }
    }

    const int rbase = blockIdx.x * 64;
    for (int i = tid; i < 64 * 64; i += 256) {
        int r = i >> 6, c = i & 63;
        int gr = rbase + r;
        float2 v = (gr < nrows) ? *reinterpret_cast<const float2*>(&X[(size_t)gr * NF + 2 * c])
                                : make_float2(0.f, 0.f);
        sx[r * 136 + 2 * c]     = (__bf16)v.x;
        sx[r * 136 + 2 * c + 1] = (__bf16)v.y;
    }
    __syncthreads();

    f32x4 acc[4][2];
    #pragma unroll
    for (int mt = 0; mt < 4; ++mt)
        #pragma unroll
        for (int nt = 0; nt < 2; ++nt)
            acc[mt][nt] = f32x4{rb1[nt], rb1[nt], rb1[nt], rb1[nt]};
    #pragma unroll
    for (int kc = 0; kc < 4; ++kc) {
        bf16x8 af[4];
        #pragma unroll
        for (int mt = 0; mt < 4; ++mt)
            af[mt] = *reinterpret_cast<const bf16x8*>(&sx[(mt * 16 + col) * 136 + kc * 32 + quad * 8]);
        #pragma unroll
        for (int mt = 0; mt < 4; ++mt)
            #pragma unroll
            for (int nt = 0; nt < 2; ++nt)
                acc[mt][nt] = __builtin_amdgcn_mfma_f32_16x16x32_bf16(af[mt], wf1[nt][kc], acc[mt][nt], 0, 0, 0);
    }
    #pragma unroll
    for (int mt = 0; mt < 4; ++mt)
        #pragma unroll
        for (int nt = 0; nt < 2; ++nt)
            #pragma unroll
            for (int r = 0; r < 4; ++r)
                st[(mt * 16 + quad * 4 + r) * 136 + wv * 32 + nt * 16 + col] = (__bf16)ssp_f(acc[mt][nt][r]);
    __syncthreads();

    f32x4 acc2[4][2];
    #pragma unroll
    for (int mt = 0; mt < 4; ++mt)
        #pragma unroll
        for (int nt = 0; nt < 2; ++nt)
            acc2[mt][nt] = f32x4{rb2[nt], rb2[nt], rb2[nt], rb2[nt]};
    #pragma unroll
    for (int kc = 0; kc < 4; ++kc) {
        bf16x8 af[4];
        #pragma unroll
        for (int mt = 0; mt < 4; ++mt)
            af[mt] = *reinterpret_cast<const bf16x8*>(&st[(mt * 16 + col) * 136 + kc * 32 + quad * 8]);
        #pragma unroll
        for (int mt = 0; mt < 4; ++mt)
            #pragma unroll
            for (int nt = 0; nt < 2; ++nt)
                acc2[mt][nt] = __builtin_amdgcn_mfma_f32_16x16x32_bf16(af[mt], wf2[nt][kc], acc2[mt][nt], 0, 0, 0);
    }
    #pragma unroll
    for (int mt = 0; mt < 4; ++mt)
        #pragma unroll
        for (int nt = 0; nt < 2; ++nt)
            #pragma unroll
            for (int r = 0; r < 4; ++r) {
                int row = rbase + mt * 16 + quad * 4 + r;
                if (row < nrows) Y[(size_t)row * NF + wv * 32 + nt * 16 + col] = acc2[mt][nt][r];
            }
}

// ---------------- single-pass CSR edge kernel: MLP + gather + per-node reduce ----------------
// v3 changes vs the 555-us baseline:
//  * __launch_bounds__(256,3): force VGPR <= 168 -> 3 waves/SIMD (was 200 -> 2).
//  * w1 fragment table moved from LDS to a precomputed 16-KB global buffer
//    (L1-resident); LDS drops 58.4 -> 41.5 KB -> 3 blocks/CU (was 2).
//  * dynamic work-stealing over nodes (atomic counter) instead of a static
//    5-nodes-per-wave partition: removes block-round quantization + degree tail.
__global__ __launch_bounds__(256, 3) void k_edge_csr(
    const int* __restrict__ off, const int* __restrict__ perm,
    const int* __restrict__ srcs, const float* __restrict__ Cs,
    const float* __restrict__ ea,
    const __bf16* __restrict__ w1fg, const float* __restrict__ b1,
    const float* __restrict__ w2, const float* __restrict__ b2,
    const float* __restrict__ h, float* __restrict__ agg,
    int* __restrict__ wctr)
{
    __shared__ alignas(16) __bf16 w2f[32 * 64 * 8];   // 32 KB, frag = ntg*4+kc
    __shared__ alignas(16) __bf16 st1[4][16 * 68];    // 8.5 KB, wave-private halves

    const int tid  = threadIdx.x;
    const int wv   = tid >> 6, lane = tid & 63;
    const int col  = lane & 15, quad = lane >> 4;

    // stage w2 B-fragments (one-time)
    for (int idx = tid; idx < 32 * 64; idx += 256) {
        int fr = idx >> 6, l = idx & 63;
        int ntg = fr >> 2, kc = fr & 3;
        int n = ntg * 16 + (l & 15), kb = kc * 32 + (l >> 4) * 8;
        __bf16* d = &w2f[idx * 8];
        #pragma unroll
        for (int j = 0; j < 8; ++j)
            d[j] = (__bf16)w2[(kb + j) * NF + n];
    }
    float rb1[8], rb2[8];
    #pragma unroll
    for (int nt = 0; nt < 8; ++nt) { rb1[nt] = b1[nt * 16 + col]; rb2[nt] = b2[nt * 16 + col]; }
    __syncthreads();   // the only barrier

    __bf16* myst = st1[wv];

    for (;;) {
        int n;
        if (lane == 0) n = atomicAdd(wctr, 1);
        n = __shfl(n, 0, 64);
        if (n >= NNODES) break;

        const int s = off[n], eend = off[n + 1];

        float pacc[8] = {0.f, 0.f, 0.f, 0.f, 0.f, 0.f, 0.f, 0.f};

        for (int base = s; base < eend; base += 16) {
            // per-lane slot (col dimension); lanes 16-63 duplicate cols 0-15
            int pos  = base + col;
            int lpos = min(pos, NEDGES - 1);
            int eidc = perm[lpos];
            int srcc = srcs[lpos];
            float Cv = (pos < eend) ? Cs[lpos] : 0.0f;

            // per-row (quad*4+r) metadata via cross-lane pull
            int   src_r[4];
            float Cw[4];
            #pragma unroll
            for (int r = 0; r < 4; ++r) {
                int sl = quad * 4 + r;
                src_r[r] = __shfl(srcc, sl, 64);
                Cw[r]    = __shfl(Cv,   sl, 64);
            }

            // hoisted gathers (hide behind the MLP)
            float hg[8][4];
            #pragma unroll
            for (int nt = 0; nt < 8; ++nt)
                #pragma unroll
                for (int r = 0; r < 4; ++r)
                    hg[nt][r] = h[(size_t)src_r[r] * NF + nt * 16 + col];

            // layer-1 A-frags from ea[eidc] (row = col)
            const float* erow = ea + (size_t)eidc * NB;
            bf16x8 af0, af1;
            #pragma unroll
            for (int p = 0; p < 4; ++p) {
                float2 v = *reinterpret_cast<const float2*>(erow + quad * 8 + 2 * p);
                af0[2 * p]     = (__bf16)v.x;
                af0[2 * p + 1] = (__bf16)v.y;
            }
            #pragma unroll
            for (int p = 0; p < 4; ++p) {
                int k = 32 + quad * 8 + 2 * p;
                float2 v = (k + 2 <= NB) ? *reinterpret_cast<const float2*>(erow + k)
                                         : make_float2(0.f, 0.f);
                af1[2 * p]     = (__bf16)v.x;
                af1[2 * p + 1] = (__bf16)v.y;
            }

            f32x4 acc2[8];
            #pragma unroll
            for (int nt = 0; nt < 8; ++nt) acc2[nt] = f32x4{rb2[nt], rb2[nt], rb2[nt], rb2[nt]};

            #pragma unroll
            for (int hf = 0; hf < 2; ++hf) {
                f32x4 acc1[4];
                #pragma unroll
                for (int nt = 0; nt < 4; ++nt) {
                    int ntg = hf * 4 + nt;
                    acc1[nt] = f32x4{rb1[ntg], rb1[ntg], rb1[ntg], rb1[ntg]};
                    bf16x8 bw0 = *reinterpret_cast<const bf16x8*>(&w1fg[((ntg * 2 + 0) * 64 + lane) * 8]);
                    bf16x8 bw1 = *reinterpret_cast<const bf16x8*>(&w1fg[((ntg * 2 + 1) * 64 + lane) * 8]);
                    acc1[nt] = __builtin_amdgcn_mfma_f32_16x16x32_bf16(af0, bw0, acc1[nt], 0, 0, 0);
                    acc1[nt] = __builtin_amdgcn_mfma_f32_16x16x32_bf16(af1, bw1, acc1[nt], 0, 0, 0);
                }
                #pragma unroll
                for (int nt = 0; nt < 4; ++nt)
                    #pragma unroll
                    for (int r = 0; r < 4; ++r)
                        myst[(quad * 4 + r) * 68 + nt * 16 + col] = (__bf16)ssp_f(acc1[nt][r]);
                bf16x8 a20 = *reinterpret_cast<const bf16x8*>(&myst[col * 68 + 0 * 32 + quad * 8]);
                bf16x8 a21 = *reinterpret_cast<const bf16x8*>(&myst[col * 68 + 1 * 32 + quad * 8]);
                #pragma unroll
                for (int nt = 0; nt < 8; ++nt) {
                    bf16x8 b20 = *reinterpret_cast<const bf16x8*>(&w2f[((nt * 4 + hf * 2 + 0) * 64 + lane) * 8]);
                    bf16x8 b21 = *reinterpret_cast<const bf16x8*>(&w2f[((nt * 4 + hf * 2 + 1) * 64 + lane) * 8]);
                    acc2[nt] = __builtin_amdgcn_mfma_f32_16x16x32_bf16(a20, b20, acc2[nt], 0, 0, 0);
                    acc2[nt] = __builtin_amdgcn_mfma_f32_16x16x32_bf16(a21, b21, acc2[nt], 0, 0, 0);
                }
            }

            // accumulate this tile's contribution (padded rows have Cw=0)
            #pragma unroll
            for (int nt = 0; nt < 8; ++nt)
                #pragma unroll
                for (int r = 0; r < 4; ++r) {
                    float t = Cw[r] * hg[nt][r];
                    pacc[nt] = fmaf(acc2[nt][r], t, pacc[nt]);
                }
        }

        // cross-quad reduce (sum the 4 row-groups) and write the agg row
        #pragma unroll
        for (int nt = 0; nt < 8; ++nt) {
            float v = pacc[nt];
            v += __shfl_xor(v, 16, 64);
            v += __shfl_xor(v, 32, 64);
            if (lane < 16) agg[(size_t)n * NF + nt * 16 + lane] = v;
        }
    }
}

extern "C" void kernel_launch(void* const* d_in, const int* in_sizes, int n_in,
                              void* d_out, int out_size, void* d_ws, size_t ws_size,
                              hipStream_t stream) {
    const float* x    = (const float*)d_in[0];
    const int*   eidx = (const int*)d_in[1];
    const float* ew   = (const float*)d_in[2];
    const float* ea   = (const float*)d_in[3];
    const float* w1   = (const float*)d_in[4];
    const float* b1   = (const float*)d_in[5];
    const float* w2   = (const float*)d_in[6];
    const float* b2   = (const float*)d_in[7];
    const float* l1w  = (const float*)d_in[8];
    const float* l2w  = (const float*)d_in[9];
    const float* l2b  = (const float*)d_in[10];
    const float* lw   = (const float*)d_in[11];
    const float* lb   = (const float*)d_in[12];
    (void)in_sizes; (void)n_in; (void)out_size; (void)ws_size;

    const int* esrc = eidx;
    const int* edst = eidx + NEDGES;

    char* p = (char*)d_ws;
    float*  h    = (float*)p;  p += (size_t)NNODES * NF * 4;      // 10.24 MB
    float*  agg  = (float*)p;  p += (size_t)NNODES * NF * 4;      // 10.24 MB
    int*    off  = (int*)p;    p += (size_t)(NNODES + 4) * 4;
    int*    hist = (int*)p;    p += (size_t)NNODES * 4;
    int*    cnt  = (int*)p;    p += (size_t)NNODES * 4;
    int*    wctr = (int*)p;    p += 64 * 4;                       // work-steal counter (zeroed with hist/cnt)
    int*    bsum = (int*)p;    p += 128 * 4;
    int*    bbase= (int*)p;    p += 128 * 4;
    __bf16* w1fg = (__bf16*)p; p += 16 * 64 * 8 * 2;              // 16 KB w1 fragment table
    int*    perm = (int*)p;    p += (size_t)NEDGES * 4;           // 2.56 MB
    int*    srcs = (int*)p;    p += (size_t)NEDGES * 4;           // 2.56 MB
    float*  Cs   = (float*)p;  p += (size_t)NEDGES * 4;           // 2.56 MB

    // h = x @ lin1_w (MFMA)
    hipLaunchKernelGGL(k_node1, dim3(313), dim3(256), 0, stream, x, l1w, h, NNODES);

    // w1 fragment table (16 KB)
    hipLaunchKernelGGL(k_prep_w1, dim3(4), dim3(256), 0, stream, w1, w1fg);

    // dst-sorted CSR build (hist -> hierarchical scan -> scatter w/ pre-gather)
    // zero range covers hist + cnt + wctr (contiguous)
    hipLaunchKernelGGL(k_zero_small, dim3(157), dim3(256), 0, stream, hist, 2 * NNODES + 64);
    hipLaunchKernelGGL(k_hist, dim3(2500), dim3(256), 0, stream, edst, hist);
    hipLaunchKernelGGL(k_bsum, dim3(NBLK_SCAN), dim3(256), 0, stream, hist, bsum);
    hipLaunchKernelGGL(k_scan_b, dim3(1), dim3(64), 0, stream, bsum, bbase);
    hipLaunchKernelGGL(k_off, dim3(NBLK_SCAN), dim3(256), 0, stream, hist, bbase, off);
    hipLaunchKernelGGL(k_scatter, dim3(2500), dim3(256), 0, stream,
                       esrc, edst, ew, off, cnt, perm, srcs, Cs);

    // single-pass fused edge MLP + CFConv + per-node reduce (work-stealing, no atomics on data)
    hipLaunchKernelGGL(k_edge_csr, dim3(768), dim3(256), 0, stream,
                       off, perm, srcs, Cs, ea, w1fg, b1, w2, b2, h, agg, wctr);

    // out = ssp(agg @ lin2_w + lin2_b) @ lin_w + lin_b (fused MFMA)
    hipLaunchKernelGGL(k_tail, dim3(313), dim3(256), 0, stream,
                       agg, l2w, l2b, lw, lb, (float*)d_out, NNODES);
}

// Round 5
// 626.708 us; speedup vs baseline: 1.5083x; 1.5083x over previous
//
#include <hip/hip_runtime.h>
#include <hip/hip_bf16.h>

#define NNODES 20000
#define NEDGES 640000
#define NB 50
#define NF 128
#define NBLK_SCAN 79   // ceil(20000/256)

typedef unsigned int uint_t;
typedef unsigned short ushort_t;

typedef __bf16 bf16x8 __attribute__((ext_vector_type(8)));
typedef float f32x4 __attribute__((ext_vector_type(4)));

// fast shifted softplus: hardware v_exp_f32 / v_log_f32
__device__ __forceinline__ float ssp_f(float x) {
    float t = __expf(-fabsf(x));
    return fmaxf(x, 0.0f) + __logf(1.0f + t) - 0.6931471805599453f;
}

__device__ __forceinline__ uint_t pack2bf(float a, float b) {
    union { __bf16 h[2]; uint_t u; } t;
    t.h[0] = (__bf16)a; t.h[1] = (__bf16)b;
    return t.u;
}

// ---------------- zero hist + cnt + work counter ----------------
__global__ __launch_bounds__(256) void k_zero_small(int* __restrict__ p, int n) {
    int i = blockIdx.x * 256 + threadIdx.x;
    if (i < n) p[i] = 0;
}

// ---------------- histogram of dst ----------------
__global__ __launch_bounds__(256) void k_hist(const int* __restrict__ dst, int* __restrict__ hist) {
    int i = blockIdx.x * 256 + threadIdx.x;
    if (i < NEDGES) atomicAdd(&hist[dst[i]], 1);
}

// ---------------- hierarchical exclusive scan: blocksums ----------------
__global__ __launch_bounds__(256) void k_bsum(const int* __restrict__ hist, int* __restrict__ bsum) {
    __shared__ int ws[4];
    int i = blockIdx.x * 256 + threadIdx.x;
    int v = (i < NNODES) ? hist[i] : 0;
    #pragma unroll
    for (int s = 1; s < 64; s <<= 1) v += __shfl_xor(v, s, 64);
    if ((threadIdx.x & 63) == 0) ws[threadIdx.x >> 6] = v;
    __syncthreads();
    if (threadIdx.x == 0) bsum[blockIdx.x] = ws[0] + ws[1] + ws[2] + ws[3];
}

__global__ __launch_bounds__(64) void k_scan_b(const int* __restrict__ bsum, int* __restrict__ bbase) {
    if (threadIdx.x == 0) {
        int acc = 0;
        for (int b = 0; b < NBLK_SCAN; ++b) { bbase[b] = acc; acc += bsum[b]; }
    }
}

__global__ __launch_bounds__(256) void k_off(const int* __restrict__ hist, const int* __restrict__ bbase,
                                             int* __restrict__ off) {
    __shared__ int buf[256];
    int i = blockIdx.x * 256 + threadIdx.x;
    int v = (i < NNODES) ? hist[i] : 0;
    buf[threadIdx.x] = v;
    __syncthreads();
    #pragma unroll
    for (int s = 1; s < 256; s <<= 1) {
        int t = (threadIdx.x >= (unsigned)s) ? buf[threadIdx.x - s] : 0;
        __syncthreads();
        buf[threadIdx.x] += t;
        __syncthreads();
    }
    if (i < NNODES) off[i] = bbase[blockIdx.x] + buf[threadIdx.x] - v;
    if (i == NNODES) off[NNODES] = NEDGES;
}

// ---------------- scatter: dst-grouped srcs + cutoff + PRE-PACKED bf16 ea rows ----------------
// eab[pos] = 64 bf16 (128 B, full cache line): ea[i][0..49] converted, 50..63 zero.
// Read of ea is coalesced (consecutive threads, consecutive 200-B rows);
// write is scattered but always a full aligned 128-B line -> no RMW.
__global__ __launch_bounds__(256) void k_scatter(const int* __restrict__ src, const int* __restrict__ dst,
                                                 const float* __restrict__ ew, const float* __restrict__ ea,
                                                 const int* __restrict__ off, int* __restrict__ cnt,
                                                 int* __restrict__ srcs, float* __restrict__ Cs,
                                                 __bf16* __restrict__ eab) {
    int i = blockIdx.x * 256 + threadIdx.x;
    if (i < NEDGES) {
        int d = dst[i];
        int pos = off[d] + atomicAdd(&cnt[d], 1);
        srcs[pos] = src[i];
        Cs[pos]   = 0.5f * (__cosf(ew[i] * 0.31415926535897931f) + 1.0f);

        const float* er = ea + (size_t)i * NB;
        uint_t buf[32];
        #pragma unroll
        for (int p = 0; p < 25; ++p) {
            float2 v = *reinterpret_cast<const float2*>(er + 2 * p);
            buf[p] = pack2bf(v.x, v.y);
        }
        #pragma unroll
        for (int p = 25; p < 32; ++p) buf[p] = 0;
        uint4* d4 = reinterpret_cast<uint4*>(eab + (size_t)pos * 64);
        #pragma unroll
        for (int q = 0; q < 8; ++q)
            d4[q] = make_uint4(buf[4 * q], buf[4 * q + 1], buf[4 * q + 2], buf[4 * q + 3]);
    }
}

// ---------------- node GEMM: Y = X @ W  (MFMA, 64-row tile) ----------------
__global__ __launch_bounds__(256) void k_node1(const float* __restrict__ X,
                                               const float* __restrict__ W,
                                               float* __restrict__ Y, int nrows)
{
    __shared__ alignas(16) __bf16 sx[64 * 136];
    const int tid  = threadIdx.x;
    const int wv   = tid >> 6, lane = tid & 63;
    const int col  = lane & 15, quad = lane >> 4;

    bf16x8 wf[2][4];
    #pragma unroll
    for (int nt = 0; nt < 2; ++nt) {
        int n = wv * 32 + nt * 16 + col;
        #pragma unroll
        for (int kc = 0; kc < 4; ++kc)
            #pragma unroll
            for (int j = 0; j < 8; ++j)
                wf[nt][kc][j] = (__bf16)W[(kc * 32 + quad * 8 + j) * NF + n];
    }

    const int rbase = blockIdx.x * 64;
    for (int i = tid; i < 64 * 64; i += 256) {
        int r = i >> 6, c = i & 63;
        int gr = rbase + r;
        float2 v = (gr < nrows) ? *reinterpret_cast<const float2*>(&X[(size_t)gr * NF + 2 * c])
                                : make_float2(0.f, 0.f);
        sx[r * 136 + 2 * c]     = (__bf16)v.x;
        sx[r * 136 + 2 * c + 1] = (__bf16)v.y;
    }
    __syncthreads();

    f32x4 acc[4][2] = {};
    #pragma unroll
    for (int kc = 0; kc < 4; ++kc) {
        bf16x8 af[4];
        #pragma unroll
        for (int mt = 0; mt < 4; ++mt)
            af[mt] = *reinterpret_cast<const bf16x8*>(&sx[(mt * 16 + col) * 136 + kc * 32 + quad * 8]);
        #pragma unroll
        for (int mt = 0; mt < 4; ++mt)
            #pragma unroll
            for (int nt = 0; nt < 2; ++nt)
                acc[mt][nt] = __builtin_amdgcn_mfma_f32_16x16x32_bf16(af[mt], wf[nt][kc], acc[mt][nt], 0, 0, 0);
    }
    #pragma unroll
    for (int mt = 0; mt < 4; ++mt)
        #pragma unroll
        for (int nt = 0; nt < 2; ++nt)
            #pragma unroll
            for (int r = 0; r < 4; ++r) {
                int row = rbase + mt * 16 + quad * 4 + r;
                if (row < nrows) Y[(size_t)row * NF + wv * 32 + nt * 16 + col] = acc[mt][nt][r];
            }
}

// ---------------- fused tail: out = ssp(X @ W1 + b1) @ W2 + b2 ----------------
__global__ __launch_bounds__(256) void k_tail(const float* __restrict__ X,
                                              const float* __restrict__ W1, const float* __restrict__ B1,
                                              const float* __restrict__ W2, const float* __restrict__ B2,
                                              float* __restrict__ Y, int nrows)
{
    __shared__ alignas(16) __bf16 sx[64 * 136];
    __shared__ alignas(16) __bf16 st[64 * 136];
    const int tid  = threadIdx.x;
    const int wv   = tid >> 6, lane = tid & 63;
    const int col  = lane & 15, quad = lane >> 4;

    bf16x8 wf1[2][4], wf2[2][4];
    float rb1[2], rb2[2];
    #pragma unroll
    for (int nt = 0; nt < 2; ++nt) {
        int n = wv * 32 + nt * 16 + col;
        rb1[nt] = B1[n]; rb2[nt] = B2[n];
        #pragma unroll
        for (int kc = 0; kc < 4; ++kc)
            #pragma unroll
            for (int j = 0; j < 8; ++j) {
                int k = kc * 32 + quad * 8 + j;
                wf1[nt][kc][j] = (__bf16)W1[k * NF + n];
                wf2[nt][kc][j] = (__bf16)W2[k * NF + n];
            }
    }

    const int rbase = blockIdx.x * 64;
    for (int i = tid; i < 64 * 64; i += 256) {
        int r = i >> 6, c = i & 63;
        int gr = rbase + r;
        float2 v = (gr < nrows) ? *reinterpret_cast<const float2*>(&X[(size_t)gr * NF + 2 * c])
                                : make_float2(0.f, 0.f);
        sx[r * 136 + 2 * c]     = (__bf16)v.x;
        sx[r * 136 + 2 * c + 1] = (__bf16)v.y;
    }
    __syncthreads();

    f32x4 acc[4][2];
    #pragma unroll
    for (int mt = 0; mt < 4; ++mt)
        #pragma unroll
        for (int nt = 0; nt < 2; ++nt)
            acc[mt][nt] = f32x4{rb1[nt], rb1[nt], rb1[nt], rb1[nt]};
    #pragma unroll
    for (int kc = 0; kc < 4; ++kc) {
        bf16x8 af[4];
        #pragma unroll
        for (int mt = 0; mt < 4; ++mt)
            af[mt] = *reinterpret_cast<const bf16x8*>(&sx[(mt * 16 + col) * 136 + kc * 32 + quad * 8]);
        #pragma unroll
        for (int mt = 0; mt < 4; ++mt)
            #pragma unroll
            for (int nt = 0; nt < 2; ++nt)
                acc[mt][nt] = __builtin_amdgcn_mfma_f32_16x16x32_bf16(af[mt], wf1[nt][kc], acc[mt][nt], 0, 0, 0);
    }
    #pragma unroll
    for (int mt = 0; mt < 4; ++mt)
        #pragma unroll
        for (int nt = 0; nt < 2; ++nt)
            #pragma unroll
            for (int r = 0; r < 4; ++r)
                st[(mt * 16 + quad * 4 + r) * 136 + wv * 32 + nt * 16 + col] = (__bf16)ssp_f(acc[mt][nt][r]);
    __syncthreads();

    f32x4 acc2[4][2];
    #pragma unroll
    for (int mt = 0; mt < 4; ++mt)
        #pragma unroll
        for (int nt = 0; nt < 2; ++nt)
            acc2[mt][nt] = f32x4{rb2[nt], rb2[nt], rb2[nt], rb2[nt]};
    #pragma unroll
    for (int kc = 0; kc < 4; ++kc) {
        bf16x8 af[4];
        #pragma unroll
        for (int mt = 0; mt < 4; ++mt)
            af[mt] = *reinterpret_cast<const bf16x8*>(&st[(mt * 16 + col) * 136 + kc * 32 + quad * 8]);
        #pragma unroll
        for (int mt = 0; mt < 4; ++mt)
            #pragma unroll
            for (int nt = 0; nt < 2; ++nt)
                acc2[mt][nt] = __builtin_amdgcn_mfma_f32_16x16x32_bf16(af[mt], wf2[nt][kc], acc2[mt][nt], 0, 0, 0);
    }
    #pragma unroll
    for (int mt = 0; mt < 4; ++mt)
        #pragma unroll
        for (int nt = 0; nt < 2; ++nt)
            #pragma unroll
            for (int r = 0; r < 4; ++r) {
                int row = rbase + mt * 16 + quad * 4 + r;
                if (row < nrows) Y[(size_t)row * NF + wv * 32 + nt * 16 + col] = acc2[mt][nt][r];
            }
}

// ---------------- single-pass CSR edge kernel: MLP + gather + per-node reduce ----------------
// Identical structure to the verified 555-us baseline (w1f/w2f in LDS, 2 waves/SIMD,
// NO launch-bounds forcing) with two changes:
//  * A-frags come from the pre-packed eab rows: 2 contiguous 16-B loads replace
//    perm load + 8 scattered float2 gathers + 16 bf16 converts (critical path cut).
//  * dynamic work-stealing (atomic node counter), 512 persistent blocks = 2/CU.
__global__ __launch_bounds__(256) void k_edge_csr(
    const int* __restrict__ off,
    const int* __restrict__ srcs, const float* __restrict__ Cs,
    const __bf16* __restrict__ eab,
    const float* __restrict__ w1, const float* __restrict__ b1,
    const float* __restrict__ w2, const float* __restrict__ b2,
    const float* __restrict__ h, float* __restrict__ agg,
    int* __restrict__ wctr)
{
    __shared__ alignas(16) __bf16 w1f[16 * 64 * 8];   // 16 KB, frag = ntg*2+kc
    __shared__ alignas(16) __bf16 w2f[32 * 64 * 8];   // 32 KB, frag = ntg*4+kc
    __shared__ alignas(16) __bf16 st1[4][16 * 72];    // 9 KB, wave-private halves

    const int tid  = threadIdx.x;
    const int wv   = tid >> 6, lane = tid & 63;
    const int col  = lane & 15, quad = lane >> 4;

    // stage weight B-fragments (one-time)
    for (int idx = tid; idx < 16 * 64; idx += 256) {
        int fr = idx >> 6, l = idx & 63;
        int ntg = fr >> 1, kc = fr & 1;
        int n = ntg * 16 + (l & 15), kb = kc * 32 + (l >> 4) * 8;
        __bf16* d = &w1f[idx * 8];
        #pragma unroll
        for (int j = 0; j < 8; ++j) {
            int k = kb + j;
            d[j] = (__bf16)((k < NB) ? w1[k * NF + n] : 0.0f);
        }
    }
    for (int idx = tid; idx < 32 * 64; idx += 256) {
        int fr = idx >> 6, l = idx & 63;
        int ntg = fr >> 2, kc = fr & 3;
        int n = ntg * 16 + (l & 15), kb = kc * 32 + (l >> 4) * 8;
        __bf16* d = &w2f[idx * 8];
        #pragma unroll
        for (int j = 0; j < 8; ++j)
            d[j] = (__bf16)w2[(kb + j) * NF + n];
    }
    float rb1[8], rb2[8];
    #pragma unroll
    for (int nt = 0; nt < 8; ++nt) { rb1[nt] = b1[nt * 16 + col]; rb2[nt] = b2[nt * 16 + col]; }
    __syncthreads();   // the only barrier

    __bf16* myst = st1[wv];

    for (;;) {
        int n;
        if (lane == 0) n = atomicAdd(wctr, 1);
        n = __shfl(n, 0, 64);
        if (n >= NNODES) break;

        const int s = off[n], eend = off[n + 1];

        float pacc[8] = {0.f, 0.f, 0.f, 0.f, 0.f, 0.f, 0.f, 0.f};

        for (int base = s; base < eend; base += 16) {
            // per-lane slot (col dimension); lanes 16-63 duplicate cols 0-15
            int pos  = base + col;
            int lpos = min(pos, NEDGES - 1);
            int srcc = srcs[lpos];
            float Cv = (pos < eend) ? Cs[lpos] : 0.0f;

            // per-row (quad*4+r) metadata via cross-lane pull
            int   src_r[4];
            float Cw[4];
            #pragma unroll
            for (int r = 0; r < 4; ++r) {
                int sl = quad * 4 + r;
                src_r[r] = __shfl(srcc, sl, 64);
                Cw[r]    = __shfl(Cv,   sl, 64);
            }

            // hoisted gathers (hide behind the MLP)
            float hg[8][4];
            #pragma unroll
            for (int nt = 0; nt < 8; ++nt)
                #pragma unroll
                for (int r = 0; r < 4; ++r)
                    hg[nt][r] = h[(size_t)src_r[r] * NF + nt * 16 + col];

            // layer-1 A-frags: direct 16-B loads from pre-packed eab row
            const __bf16* erow = eab + (size_t)lpos * 64;
            bf16x8 af0 = *reinterpret_cast<const bf16x8*>(erow + quad * 8);
            bf16x8 af1 = *reinterpret_cast<const bf16x8*>(erow + 32 + quad * 8);

            f32x4 acc2[8];
            #pragma unroll
            for (int nt = 0; nt < 8; ++nt) acc2[nt] = f32x4{rb2[nt], rb2[nt], rb2[nt], rb2[nt]};

            #pragma unroll
            for (int hf = 0; hf < 2; ++hf) {
                f32x4 acc1[4];
                #pragma unroll
                for (int nt = 0; nt < 4; ++nt) {
                    int ntg = hf * 4 + nt;
                    acc1[nt] = f32x4{rb1[ntg], rb1[ntg], rb1[ntg], rb1[ntg]};
                    bf16x8 bw0 = *reinterpret_cast<const bf16x8*>(&w1f[((ntg * 2 + 0) * 64 + lane) * 8]);
                    bf16x8 bw1 = *reinterpret_cast<const bf16x8*>(&w1f[((ntg * 2 + 1) * 64 + lane) * 8]);
                    acc1[nt] = __builtin_amdgcn_mfma_f32_16x16x32_bf16(af0, bw0, acc1[nt], 0, 0, 0);
                    acc1[nt] = __builtin_amdgcn_mfma_f32_16x16x32_bf16(af1, bw1, acc1[nt], 0, 0, 0);
                }
                #pragma unroll
                for (int nt = 0; nt < 4; ++nt)
                    #pragma unroll
                    for (int r = 0; r < 4; ++r)
                        myst[(quad * 4 + r) * 72 + nt * 16 + col] = (__bf16)ssp_f(acc1[nt][r]);
                bf16x8 a20 = *reinterpret_cast<const bf16x8*>(&myst[col * 72 + 0 * 32 + quad * 8]);
                bf16x8 a21 = *reinterpret_cast<const bf16x8*>(&myst[col * 72 + 1 * 32 + quad * 8]);
                #pragma unroll
                for (int nt = 0; nt < 8; ++nt) {
                    bf16x8 b20 = *reinterpret_cast<const bf16x8*>(&w2f[((nt * 4 + hf * 2 + 0) * 64 + lane) * 8]);
                    bf16x8 b21 = *reinterpret_cast<const bf16x8*>(&w2f[((nt * 4 + hf * 2 + 1) * 64 + lane) * 8]);
                    acc2[nt] = __builtin_amdgcn_mfma_f32_16x16x32_bf16(a20, b20, acc2[nt], 0, 0, 0);
                    acc2[nt] = __builtin_amdgcn_mfma_f32_16x16x32_bf16(a21, b21, acc2[nt], 0, 0, 0);
                }
            }

            // accumulate this tile's contribution (padded rows have Cw=0)
            #pragma unroll
            for (int nt = 0; nt < 8; ++nt)
                #pragma unroll
                for (int r = 0; r < 4; ++r) {
                    float t = Cw[r] * hg[nt][r];
                    pacc[nt] = fmaf(acc2[nt][r], t, pacc[nt]);
                }
        }

        // cross-quad reduce (sum the 4 row-groups) and write the agg row
        #pragma unroll
        for (int nt = 0; nt < 8; ++nt) {
            float v = pacc[nt];
            v += __shfl_xor(v, 16, 64);
            v += __shfl_xor(v, 32, 64);
            if (lane < 16) agg[(size_t)n * NF + nt * 16 + lane] = v;
        }
    }
}

extern "C" void kernel_launch(void* const* d_in, const int* in_sizes, int n_in,
                              void* d_out, int out_size, void* d_ws, size_t ws_size,
                              hipStream_t stream) {
    const float* x    = (const float*)d_in[0];
    const int*   eidx = (const int*)d_in[1];
    const float* ew   = (const float*)d_in[2];
    const float* ea   = (const float*)d_in[3];
    const float* w1   = (const float*)d_in[4];
    const float* b1   = (const float*)d_in[5];
    const float* w2   = (const float*)d_in[6];
    const float* b2   = (const float*)d_in[7];
    const float* l1w  = (const float*)d_in[8];
    const float* l2w  = (const float*)d_in[9];
    const float* l2b  = (const float*)d_in[10];
    const float* lw   = (const float*)d_in[11];
    const float* lb   = (const float*)d_in[12];
    (void)in_sizes; (void)n_in; (void)out_size; (void)ws_size;

    const int* esrc = eidx;
    const int* edst = eidx + NEDGES;

    char* p = (char*)d_ws;
    float*  h    = (float*)p;  p += (size_t)NNODES * NF * 4;      // 10.24 MB
    float*  agg  = (float*)p;  p += (size_t)NNODES * NF * 4;      // 10.24 MB
    int*    off  = (int*)p;    p += (size_t)(NNODES + 4) * 4;
    int*    hist = (int*)p;    p += (size_t)NNODES * 4;
    int*    cnt  = (int*)p;    p += (size_t)NNODES * 4;
    int*    wctr = (int*)p;    p += 64 * 4;                       // work-steal counter (zeroed with hist/cnt)
    int*    bsum = (int*)p;    p += 128 * 4;
    int*    bbase= (int*)p;    p += 128 * 4;
    int*    srcs = (int*)p;    p += (size_t)NEDGES * 4;           // 2.56 MB
    float*  Cs   = (float*)p;  p += (size_t)NEDGES * 4;           // 2.56 MB
    __bf16* eab  = (__bf16*)p; p += (size_t)NEDGES * 64 * 2;      // 81.92 MB pre-packed bf16 ea rows

    // h = x @ lin1_w (MFMA)
    hipLaunchKernelGGL(k_node1, dim3(313), dim3(256), 0, stream, x, l1w, h, NNODES);

    // dst-sorted CSR build (hist -> hierarchical scan -> scatter w/ pre-pack)
    // zero range covers hist + cnt + wctr (contiguous)
    hipLaunchKernelGGL(k_zero_small, dim3(157), dim3(256), 0, stream, hist, 2 * NNODES + 64);
    hipLaunchKernelGGL(k_hist, dim3(2500), dim3(256), 0, stream, edst, hist);
    hipLaunchKernelGGL(k_bsum, dim3(NBLK_SCAN), dim3(256), 0, stream, hist, bsum);
    hipLaunchKernelGGL(k_scan_b, dim3(1), dim3(64), 0, stream, bsum, bbase);
    hipLaunchKernelGGL(k_off, dim3(NBLK_SCAN), dim3(256), 0, stream, hist, bbase, off);
    hipLaunchKernelGGL(k_scatter, dim3(2500), dim3(256), 0, stream,
                       esrc, edst, ew, ea, off, cnt, srcs, Cs, eab);

    // single-pass fused edge MLP + CFConv + per-node reduce (work-stealing persistent blocks)
    hipLaunchKernelGGL(k_edge_csr, dim3(512), dim3(256), 0, stream,
                       off, srcs, Cs, eab, w1, b1, w2, b2, h, agg, wctr);

    // out = ssp(agg @ lin2_w + lin2_b) @ lin_w + lin_b (fused MFMA)
    hipLaunchKernelGGL(k_tail, dim3(313), dim3(256), 0, stream,
                       agg, l2w, l2b, lw, lb, (float*)d_out, NNODES);
}

// Round 6
// 590.424 us; speedup vs baseline: 1.6010x; 1.0615x over previous
//
#include <hip/hip_runtime.h>
#include <hip/hip_bf16.h>

#define NNODES 20000
#define NEDGES 640000
#define NB 50
#define NF 128
#define NBLK_SCAN 79   // ceil(20000/256)

typedef unsigned int uint_t;
typedef unsigned short ushort_t;

typedef __bf16 bf16x8 __attribute__((ext_vector_type(8)));
typedef float f32x4 __attribute__((ext_vector_type(4)));

// fast shifted softplus: hardware v_exp_f32 / v_log_f32
__device__ __forceinline__ float ssp_f(float x) {
    float t = __expf(-fabsf(x));
    return fmaxf(x, 0.0f) + __logf(1.0f + t) - 0.6931471805599453f;
}

__device__ __forceinline__ uint_t pack2bf(float a, float b) {
    union { __bf16 h[2]; uint_t u; } t;
    t.h[0] = (__bf16)a; t.h[1] = (__bf16)b;
    return t.u;
}

// ---------------- zero hist + cnt + work counter ----------------
__global__ __launch_bounds__(256) void k_zero_small(int* __restrict__ p, int n) {
    int i = blockIdx.x * 256 + threadIdx.x;
    if (i < n) p[i] = 0;
}

// ---------------- histogram of dst ----------------
__global__ __launch_bounds__(256) void k_hist(const int* __restrict__ dst, int* __restrict__ hist) {
    int i = blockIdx.x * 256 + threadIdx.x;
    if (i < NEDGES) atomicAdd(&hist[dst[i]], 1);
}

// ---------------- hierarchical exclusive scan: blocksums ----------------
__global__ __launch_bounds__(256) void k_bsum(const int* __restrict__ hist, int* __restrict__ bsum) {
    __shared__ int ws[4];
    int i = blockIdx.x * 256 + threadIdx.x;
    int v = (i < NNODES) ? hist[i] : 0;
    #pragma unroll
    for (int s = 1; s < 64; s <<= 1) v += __shfl_xor(v, s, 64);
    if ((threadIdx.x & 63) == 0) ws[threadIdx.x >> 6] = v;
    __syncthreads();
    if (threadIdx.x == 0) bsum[blockIdx.x] = ws[0] + ws[1] + ws[2] + ws[3];
}

__global__ __launch_bounds__(64) void k_scan_b(const int* __restrict__ bsum, int* __restrict__ bbase) {
    if (threadIdx.x == 0) {
        int acc = 0;
        for (int b = 0; b < NBLK_SCAN; ++b) { bbase[b] = acc; acc += bsum[b]; }
    }
}

__global__ __launch_bounds__(256) void k_off(const int* __restrict__ hist, const int* __restrict__ bbase,
                                             int* __restrict__ off) {
    __shared__ int buf[256];
    int i = blockIdx.x * 256 + threadIdx.x;
    int v = (i < NNODES) ? hist[i] : 0;
    buf[threadIdx.x] = v;
    __syncthreads();
    #pragma unroll
    for (int s = 1; s < 256; s <<= 1) {
        int t = (threadIdx.x >= (unsigned)s) ? buf[threadIdx.x - s] : 0;
        __syncthreads();
        buf[threadIdx.x] += t;
        __syncthreads();
    }
    if (i < NNODES) off[i] = bbase[blockIdx.x] + buf[threadIdx.x] - v;
    if (i == NNODES) off[NNODES] = NEDGES;
}

// ---------------- scatter: dst-grouped perm + pre-gathered src + cutoff (round-0 form) ----------------
__global__ __launch_bounds__(256) void k_scatter(const int* __restrict__ src, const int* __restrict__ dst,
                                                 const float* __restrict__ ew,
                                                 const int* __restrict__ off, int* __restrict__ cnt,
                                                 int* __restrict__ perm, int* __restrict__ srcs,
                                                 float* __restrict__ Cs) {
    int i = blockIdx.x * 256 + threadIdx.x;
    if (i < NEDGES) {
        int d = dst[i];
        int pos = off[d] + atomicAdd(&cnt[d], 1);
        perm[pos] = i;
        srcs[pos] = src[i];
        Cs[pos]   = 0.5f * (__cosf(ew[i] * 0.31415926535897931f) + 1.0f);
    }
}

// ---------------- node GEMM: Y = X @ W  (MFMA, 64-row tile) ----------------
__global__ __launch_bounds__(256) void k_node1(const float* __restrict__ X,
                                               const float* __restrict__ W,
                                               float* __restrict__ Y, int nrows)
{
    __shared__ alignas(16) __bf16 sx[64 * 136];
    const int tid  = threadIdx.x;
    const int wv   = tid >> 6, lane = tid & 63;
    const int col  = lane & 15, quad = lane >> 4;

    bf16x8 wf[2][4];
    #pragma unroll
    for (int nt = 0; nt < 2; ++nt) {
        int n = wv * 32 + nt * 16 + col;
        #pragma unroll
        for (int kc = 0; kc < 4; ++kc)
            #pragma unroll
            for (int j = 0; j < 8; ++j)
                wf[nt][kc][j] = (__bf16)W[(kc * 32 + quad * 8 + j) * NF + n];
    }

    const int rbase = blockIdx.x * 64;
    for (int i = tid; i < 64 * 64; i += 256) {
        int r = i >> 6, c = i & 63;
        int gr = rbase + r;
        float2 v = (gr < nrows) ? *reinterpret_cast<const float2*>(&X[(size_t)gr * NF + 2 * c])
                                : make_float2(0.f, 0.f);
        sx[r * 136 + 2 * c]     = (__bf16)v.x;
        sx[r * 136 + 2 * c + 1] = (__bf16)v.y;
    }
    __syncthreads();

    f32x4 acc[4][2] = {};
    #pragma unroll
    for (int kc = 0; kc < 4; ++kc) {
        bf16x8 af[4];
        #pragma unroll
        for (int mt = 0; mt < 4; ++mt)
            af[mt] = *reinterpret_cast<const bf16x8*>(&sx[(mt * 16 + col) * 136 + kc * 32 + quad * 8]);
        #pragma unroll
        for (int mt = 0; mt < 4; ++mt)
            #pragma unroll
            for (int nt = 0; nt < 2; ++nt)
                acc[mt][nt] = __builtin_amdgcn_mfma_f32_16x16x32_bf16(af[mt], wf[nt][kc], acc[mt][nt], 0, 0, 0);
    }
    #pragma unroll
    for (int mt = 0; mt < 4; ++mt)
        #pragma unroll
        for (int nt = 0; nt < 2; ++nt)
            #pragma unroll
            for (int r = 0; r < 4; ++r) {
                int row = rbase + mt * 16 + quad * 4 + r;
                if (row < nrows) Y[(size_t)row * NF + wv * 32 + nt * 16 + col] = acc[mt][nt][r];
            }
}

// ---------------- fused tail: out = ssp(X @ W1 + b1) @ W2 + b2 ----------------
__global__ __launch_bounds__(256) void k_tail(const float* __restrict__ X,
                                              const float* __restrict__ W1, const float* __restrict__ B1,
                                              const float* __restrict__ W2, const float* __restrict__ B2,
                                              float* __restrict__ Y, int nrows)
{
    __shared__ alignas(16) __bf16 sx[64 * 136];
    __shared__ alignas(16) __bf16 st[64 * 136];
    const int tid  = threadIdx.x;
    const int wv   = tid >> 6, lane = tid & 63;
    const int col  = lane & 15, quad = lane >> 4;

    bf16x8 wf1[2][4], wf2[2][4];
    float rb1[2], rb2[2];
    #pragma unroll
    for (int nt = 0; nt < 2; ++nt) {
        int n = wv * 32 + nt * 16 + col;
        rb1[nt] = B1[n]; rb2[nt] = B2[n];
        #pragma unroll
        for (int kc = 0; kc < 4; ++kc)
            #pragma unroll
            for (int j = 0; j < 8; ++j) {
                int k = kc * 32 + quad * 8 + j;
                wf1[nt][kc][j] = (__bf16)W1[k * NF + n];
                wf2[nt][kc][j] = (__bf16)W2[k * NF + n];
            }
    }

    const int rbase = blockIdx.x * 64;
    for (int i = tid; i < 64 * 64; i += 256) {
        int r = i >> 6, c = i & 63;
        int gr = rbase + r;
        float2 v = (gr < nrows) ? *reinterpret_cast<const float2*>(&X[(size_t)gr * NF + 2 * c])
                                : make_float2(0.f, 0.f);
        sx[r * 136 + 2 * c]     = (__bf16)v.x;
        sx[r * 136 + 2 * c + 1] = (__bf16)v.y;
    }
    __syncthreads();

    f32x4 acc[4][2];
    #pragma unroll
    for (int mt = 0; mt < 4; ++mt)
        #pragma unroll
        for (int nt = 0; nt < 2; ++nt)
            acc[mt][nt] = f32x4{rb1[nt], rb1[nt], rb1[nt], rb1[nt]};
    #pragma unroll
    for (int kc = 0; kc < 4; ++kc) {
        bf16x8 af[4];
        #pragma unroll
        for (int mt = 0; mt < 4; ++mt)
            af[mt] = *reinterpret_cast<const bf16x8*>(&sx[(mt * 16 + col) * 136 + kc * 32 + quad * 8]);
        #pragma unroll
        for (int mt = 0; mt < 4; ++mt)
            #pragma unroll
            for (int nt = 0; nt < 2; ++nt)
                acc[mt][nt] = __builtin_amdgcn_mfma_f32_16x16x32_bf16(af[mt], wf1[nt][kc], acc[mt][nt], 0, 0, 0);
    }
    #pragma unroll
    for (int mt = 0; mt < 4; ++mt)
        #pragma unroll
        for (int nt = 0; nt < 2; ++nt)
            #pragma unroll
            for (int r = 0; r < 4; ++r)
                st[(mt * 16 + quad * 4 + r) * 136 + wv * 32 + nt * 16 + col] = (__bf16)ssp_f(acc[mt][nt][r]);
    __syncthreads();

    f32x4 acc2[4][2];
    #pragma unroll
    for (int mt = 0; mt < 4; ++mt)
        #pragma unroll
        for (int nt = 0; nt < 2; ++nt)
            acc2[mt][nt] = f32x4{rb2[nt], rb2[nt], rb2[nt], rb2[nt]};
    #pragma unroll
    for (int kc = 0; kc < 4; ++kc) {
        bf16x8 af[4];
        #pragma unroll
        for (int mt = 0; mt < 4; ++mt)
            af[mt] = *reinterpret_cast<const bf16x8*>(&st[(mt * 16 + col) * 136 + kc * 32 + quad * 8]);
        #pragma unroll
        for (int mt = 0; mt < 4; ++mt)
            #pragma unroll
            for (int nt = 0; nt < 2; ++nt)
                acc2[mt][nt] = __builtin_amdgcn_mfma_f32_16x16x32_bf16(af[mt], wf2[nt][kc], acc2[mt][nt], 0, 0, 0);
    }
    #pragma unroll
    for (int mt = 0; mt < 4; ++mt)
        #pragma unroll
        for (int nt = 0; nt < 2; ++nt)
            #pragma unroll
            for (int r = 0; r < 4; ++r) {
                int row = rbase + mt * 16 + quad * 4 + r;
                if (row < nrows) Y[(size_t)row * NF + wv * 32 + nt * 16 + col] = acc2[mt][nt][r];
            }
}

// ---------------- single-pass CSR edge kernel: swapped-L1 MLP, no LDS transpose ----------------
// Layer-1 computed TRANSPOSED: t1^T = mfma(A=W1-frag, B=ea-frag) -- for 16x16x32 the
// A- and B-frag lane layouts are identical, so the same w1f/af fragments are used with
// operand order swapped. Lane (e=lane&15) then holds t1[e][f1=ntg*16+quad*4+r].
// Layer-2 A-frags are rebuilt in-register: pack to bf16 pairs, 8 shfl + 4 select per
// kc2 (sources (quad&1)*32+e and +16; register choice by quad>>1). Layer-1 bias is
// folded into the k=50 pad slot (ea^T[50][e]=1, W1-frag row 50 = b1). st1 LDS is gone
// (58.4 -> 48 KB -> 3 blocks/CU). Layer-2 output layout is unchanged, so the
// Cw/hg/pacc/reduce code is byte-identical to the verified baseline.
__global__ __launch_bounds__(256) void k_edge_csr(
    const int* __restrict__ off, const int* __restrict__ perm,
    const int* __restrict__ srcs, const float* __restrict__ Cs,
    const float* __restrict__ ea,
    const float* __restrict__ w1, const float* __restrict__ b1,
    const float* __restrict__ w2, const float* __restrict__ b2,
    const float* __restrict__ h, float* __restrict__ agg,
    int* __restrict__ wctr)
{
    __shared__ alignas(16) __bf16 w1f[16 * 64 * 8];   // 16 KB, frag = ntg*2+kc
    __shared__ alignas(16) __bf16 w2f[32 * 64 * 8];   // 32 KB, frag = nt*4+kc2

    const int tid  = threadIdx.x;
    const int lane = tid & 63;
    const int col  = lane & 15, quad = lane >> 4;

    // stage weight fragments (one-time). w1f row k=50 carries b1 (bias-in-pad trick).
    for (int idx = tid; idx < 16 * 64; idx += 256) {
        int fr = idx >> 6, l = idx & 63;
        int ntg = fr >> 1, kc = fr & 1;
        int n = ntg * 16 + (l & 15), kb = kc * 32 + (l >> 4) * 8;
        __bf16* d = &w1f[idx * 8];
        #pragma unroll
        for (int j = 0; j < 8; ++j) {
            int k = kb + j;
            float v = (k < NB) ? w1[k * NF + n] : ((k == NB) ? b1[n] : 0.0f);
            d[j] = (__bf16)v;
        }
    }
    for (int idx = tid; idx < 32 * 64; idx += 256) {
        int fr = idx >> 6, l = idx & 63;
        int ntg = fr >> 2, kc = fr & 3;
        int n = ntg * 16 + (l & 15), kb = kc * 32 + (l >> 4) * 8;
        __bf16* d = &w2f[idx * 8];
        #pragma unroll
        for (int j = 0; j < 8; ++j)
            d[j] = (__bf16)w2[(kb + j) * NF + n];
    }
    float rb2[8];
    #pragma unroll
    for (int nt = 0; nt < 8; ++nt) rb2[nt] = b2[nt * 16 + col];
    __syncthreads();   // the only barrier

    const int s0lane = (quad & 1) * 32 + col;   // shuffle source for j=0..3
    const int s1lane = s0lane + 16;             // shuffle source for j=4..7
    const bool hisel = (quad >> 1) != 0;        // register choice: ntg' = 2*kc2 + (quad>>1)

    for (;;) {
        int n;
        if (lane == 0) n = atomicAdd(wctr, 1);
        n = __shfl(n, 0, 64);
        if (n >= NNODES) break;

        const int s = off[n], eend = off[n + 1];

        float pacc[8] = {0.f, 0.f, 0.f, 0.f, 0.f, 0.f, 0.f, 0.f};

        for (int base = s; base < eend; base += 16) {
            // per-lane slot (col dimension); lanes 16-63 duplicate cols 0-15
            int pos  = base + col;
            int lpos = min(pos, NEDGES - 1);
            int eidc = perm[lpos];
            int srcc = srcs[lpos];
            float Cv = (pos < eend) ? Cs[lpos] : 0.0f;

            // per-row (quad*4+r) metadata via cross-lane pull
            int   src_r[4];
            float Cw[4];
            #pragma unroll
            for (int r = 0; r < 4; ++r) {
                int sl = quad * 4 + r;
                src_r[r] = __shfl(srcc, sl, 64);
                Cw[r]    = __shfl(Cv,   sl, 64);
            }

            // hoisted gathers (hide behind the MLP)
            float hg[8][4];
            #pragma unroll
            for (int nt = 0; nt < 8; ++nt)
                #pragma unroll
                for (int r = 0; r < 4; ++r)
                    hg[nt][r] = h[(size_t)src_r[r] * NF + nt * 16 + col];

            // ea fragments (row = col); k=50 pad slot set to 1.0 for the bias trick
            const float* erow = ea + (size_t)eidc * NB;
            bf16x8 af0, af1;
            #pragma unroll
            for (int p = 0; p < 4; ++p) {
                float2 v = *reinterpret_cast<const float2*>(erow + quad * 8 + 2 * p);
                af0[2 * p]     = (__bf16)v.x;
                af0[2 * p + 1] = (__bf16)v.y;
            }
            #pragma unroll
            for (int p = 0; p < 4; ++p) {
                int k = 32 + quad * 8 + 2 * p;
                float2 v;
                if (k + 2 <= NB)      v = *reinterpret_cast<const float2*>(erow + k);
                else if (k == NB)     v = make_float2(1.0f, 0.f);   // bias slot
                else                  v = make_float2(0.f, 0.f);
                af1[2 * p]     = (__bf16)v.x;
                af1[2 * p + 1] = (__bf16)v.y;
            }

            // ---- layer 1, swapped: acc1s[ntg][r] = t1[e=col][f1=ntg*16+quad*4+r]
            f32x4 acc1s[8];
            #pragma unroll
            for (int ntg = 0; ntg < 8; ++ntg) {
                acc1s[ntg] = f32x4{0.f, 0.f, 0.f, 0.f};
                bf16x8 aw0 = *reinterpret_cast<const bf16x8*>(&w1f[((ntg * 2 + 0) * 64 + lane) * 8]);
                bf16x8 aw1 = *reinterpret_cast<const bf16x8*>(&w1f[((ntg * 2 + 1) * 64 + lane) * 8]);
                acc1s[ntg] = __builtin_amdgcn_mfma_f32_16x16x32_bf16(aw0, af0, acc1s[ntg], 0, 0, 0);
                acc1s[ntg] = __builtin_amdgcn_mfma_f32_16x16x32_bf16(aw1, af1, acc1s[ntg], 0, 0, 0);
            }

            // ssp + pack to bf16 pairs: pk[ntg][p] = (t1[e][f1b+2p], t1[e][f1b+2p+1])
            uint_t pk[8][2];
            #pragma unroll
            for (int ntg = 0; ntg < 8; ++ntg) {
                pk[ntg][0] = pack2bf(ssp_f(acc1s[ntg][0]), ssp_f(acc1s[ntg][1]));
                pk[ntg][1] = pack2bf(ssp_f(acc1s[ntg][2]), ssp_f(acc1s[ntg][3]));
            }

            // ---- layer 2: rebuild A-frags in-register, then MFMA with w2f
            f32x4 acc2[8];
            #pragma unroll
            for (int nt = 0; nt < 8; ++nt) acc2[nt] = f32x4{rb2[nt], rb2[nt], rb2[nt], rb2[nt]};

            #pragma unroll
            for (int kc2 = 0; kc2 < 4; ++kc2) {
                uint_t a00 = __shfl((int)pk[2 * kc2][0],     s0lane, 64);
                uint_t b00 = __shfl((int)pk[2 * kc2 + 1][0], s0lane, 64);
                uint_t a01 = __shfl((int)pk[2 * kc2][1],     s0lane, 64);
                uint_t b01 = __shfl((int)pk[2 * kc2 + 1][1], s0lane, 64);
                uint_t a10 = __shfl((int)pk[2 * kc2][0],     s1lane, 64);
                uint_t b10 = __shfl((int)pk[2 * kc2 + 1][0], s1lane, 64);
                uint_t a11 = __shfl((int)pk[2 * kc2][1],     s1lane, 64);
                uint_t b11 = __shfl((int)pk[2 * kc2 + 1][1], s1lane, 64);
                union { uint_t u[4]; bf16x8 v; } af2;
                af2.u[0] = hisel ? b00 : a00;
                af2.u[1] = hisel ? b01 : a01;
                af2.u[2] = hisel ? b10 : a10;
                af2.u[3] = hisel ? b11 : a11;
                #pragma unroll
                for (int nt = 0; nt < 8; ++nt) {
                    bf16x8 bw = *reinterpret_cast<const bf16x8*>(&w2f[((nt * 4 + kc2) * 64 + lane) * 8]);
                    acc2[nt] = __builtin_amdgcn_mfma_f32_16x16x32_bf16(af2.v, bw, acc2[nt], 0, 0, 0);
                }
            }

            // accumulate this tile's contribution (padded rows have Cw=0)
            #pragma unroll
            for (int nt = 0; nt < 8; ++nt)
                #pragma unroll
                for (int r = 0; r < 4; ++r) {
                    float t = Cw[r] * hg[nt][r];
                    pacc[nt] = fmaf(acc2[nt][r], t, pacc[nt]);
                }
        }

        // cross-quad reduce (sum the 4 row-groups) and write the agg row
        #pragma unroll
        for (int nt = 0; nt < 8; ++nt) {
            float v = pacc[nt];
            v += __shfl_xor(v, 16, 64);
            v += __shfl_xor(v, 32, 64);
            if (lane < 16) agg[(size_t)n * NF + nt * 16 + lane] = v;
        }
    }
}

extern "C" void kernel_launch(void* const* d_in, const int* in_sizes, int n_in,
                              void* d_out, int out_size, void* d_ws, size_t ws_size,
                              hipStream_t stream) {
    const float* x    = (const float*)d_in[0];
    const int*   eidx = (const int*)d_in[1];
    const float* ew   = (const float*)d_in[2];
    const float* ea   = (const float*)d_in[3];
    const float* w1   = (const float*)d_in[4];
    const float* b1   = (const float*)d_in[5];
    const float* w2   = (const float*)d_in[6];
    const float* b2   = (const float*)d_in[7];
    const float* l1w  = (const float*)d_in[8];
    const float* l2w  = (const float*)d_in[9];
    const float* l2b  = (const float*)d_in[10];
    const float* lw   = (const float*)d_in[11];
    const float* lb   = (const float*)d_in[12];
    (void)in_sizes; (void)n_in; (void)out_size; (void)ws_size;

    const int* esrc = eidx;
    const int* edst = eidx + NEDGES;

    char* p = (char*)d_ws;
    float*  h    = (float*)p;  p += (size_t)NNODES * NF * 4;      // 10.24 MB
    float*  agg  = (float*)p;  p += (size_t)NNODES * NF * 4;      // 10.24 MB
    int*    off  = (int*)p;    p += (size_t)(NNODES + 4) * 4;
    int*    hist = (int*)p;    p += (size_t)NNODES * 4;
    int*    cnt  = (int*)p;    p += (size_t)NNODES * 4;
    int*    wctr = (int*)p;    p += 64 * 4;                       // work-steal counter (zeroed with hist/cnt)
    int*    bsum = (int*)p;    p += 128 * 4;
    int*    bbase= (int*)p;    p += 128 * 4;
    int*    perm = (int*)p;    p += (size_t)NEDGES * 4;           // 2.56 MB
    int*    srcs = (int*)p;    p += (size_t)NEDGES * 4;           // 2.56 MB
    float*  Cs   = (float*)p;  p += (size_t)NEDGES * 4;           // 2.56 MB

    // h = x @ lin1_w (MFMA)
    hipLaunchKernelGGL(k_node1, dim3(313), dim3(256), 0, stream, x, l1w, h, NNODES);

    // dst-sorted CSR build (hist -> hierarchical scan -> scatter w/ pre-gather)
    // zero range covers hist + cnt + wctr (contiguous)
    hipLaunchKernelGGL(k_zero_small, dim3(157), dim3(256), 0, stream, hist, 2 * NNODES + 64);
    hipLaunchKernelGGL(k_hist, dim3(2500), dim3(256), 0, stream, edst, hist);
    hipLaunchKernelGGL(k_bsum, dim3(NBLK_SCAN), dim3(256), 0, stream, hist, bsum);
    hipLaunchKernelGGL(k_scan_b, dim3(1), dim3(64), 0, stream, bsum, bbase);
    hipLaunchKernelGGL(k_off, dim3(NBLK_SCAN), dim3(256), 0, stream, hist, bbase, off);
    hipLaunchKernelGGL(k_scatter, dim3(2500), dim3(256), 0, stream,
                       esrc, edst, ew, off, cnt, perm, srcs, Cs);

    // single-pass fused edge MLP + CFConv + per-node reduce (swapped-L1, work-stealing)
    hipLaunchKernelGGL(k_edge_csr, dim3(768), dim3(256), 0, stream,
                       off, perm, srcs, Cs, ea, w1, b1, w2, b2, h, agg, wctr);

    // out = ssp(agg @ lin2_w + lin2_b) @ lin_w + lin_b (fused MFMA)
    hipLaunchKernelGGL(k_tail, dim3(313), dim3(256), 0, stream,
                       agg, l2w, l2b, lw, lb, (float*)d_out, NNODES);
}

// Round 7
// 582.024 us; speedup vs baseline: 1.6241x; 1.0144x over previous
//
#include <hip/hip_runtime.h>
#include <hip/hip_bf16.h>

#define NNODES 20000
#define NEDGES 640000
#define NB 50
#define NF 128
#define NBLK_SCAN 79   // ceil(20000/256)

typedef unsigned int uint_t;
typedef unsigned short ushort_t;

typedef __bf16 bf16x8 __attribute__((ext_vector_type(8)));
typedef float f32x4 __attribute__((ext_vector_type(4)));

// fast shifted softplus: hardware v_exp_f32 / v_log_f32
__device__ __forceinline__ float ssp_f(float x) {
    float t = __expf(-fabsf(x));
    return fmaxf(x, 0.0f) + __logf(1.0f + t) - 0.6931471805599453f;
}

// ---------------- zero hist + cnt + work counter ----------------
__global__ __launch_bounds__(256) void k_zero_small(int* __restrict__ p, int n) {
    int i = blockIdx.x * 256 + threadIdx.x;
    if (i < n) p[i] = 0;
}

// ---------------- histogram of dst ----------------
__global__ __launch_bounds__(256) void k_hist(const int* __restrict__ dst, int* __restrict__ hist) {
    int i = blockIdx.x * 256 + threadIdx.x;
    if (i < NEDGES) atomicAdd(&hist[dst[i]], 1);
}

// ---------------- hierarchical exclusive scan: blocksums ----------------
__global__ __launch_bounds__(256) void k_bsum(const int* __restrict__ hist, int* __restrict__ bsum) {
    __shared__ int ws[4];
    int i = blockIdx.x * 256 + threadIdx.x;
    int v = (i < NNODES) ? hist[i] : 0;
    #pragma unroll
    for (int s = 1; s < 64; s <<= 1) v += __shfl_xor(v, s, 64);
    if ((threadIdx.x & 63) == 0) ws[threadIdx.x >> 6] = v;
    __syncthreads();
    if (threadIdx.x == 0) bsum[blockIdx.x] = ws[0] + ws[1] + ws[2] + ws[3];
}

__global__ __launch_bounds__(64) void k_scan_b(const int* __restrict__ bsum, int* __restrict__ bbase) {
    if (threadIdx.x == 0) {
        int acc = 0;
        for (int b = 0; b < NBLK_SCAN; ++b) { bbase[b] = acc; acc += bsum[b]; }
    }
}

__global__ __launch_bounds__(256) void k_off(const int* __restrict__ hist, const int* __restrict__ bbase,
                                             int* __restrict__ off) {
    __shared__ int buf[256];
    int i = blockIdx.x * 256 + threadIdx.x;
    int v = (i < NNODES) ? hist[i] : 0;
    buf[threadIdx.x] = v;
    __syncthreads();
    #pragma unroll
    for (int s = 1; s < 256; s <<= 1) {
        int t = (threadIdx.x >= (unsigned)s) ? buf[threadIdx.x - s] : 0;
        __syncthreads();
        buf[threadIdx.x] += t;
        __syncthreads();
    }
    if (i < NNODES) off[i] = bbase[blockIdx.x] + buf[threadIdx.x] - v;
    if (i == NNODES) off[NNODES] = NEDGES;
}

// ---------------- scatter: dst-grouped perm + pre-gathered src + cutoff (round-0 form) ----------------
__global__ __launch_bounds__(256) void k_scatter(const int* __restrict__ src, const int* __restrict__ dst,
                                                 const float* __restrict__ ew,
                                                 const int* __restrict__ off, int* __restrict__ cnt,
                                                 int* __restrict__ perm, int* __restrict__ srcs,
                                                 float* __restrict__ Cs) {
    int i = blockIdx.x * 256 + threadIdx.x;
    if (i < NEDGES) {
        int d = dst[i];
        int pos = off[d] + atomicAdd(&cnt[d], 1);
        perm[pos] = i;
        srcs[pos] = src[i];
        Cs[pos]   = 0.5f * (__cosf(ew[i] * 0.31415926535897931f) + 1.0f);
    }
}

// ---------------- node GEMM: Y = X @ W  (MFMA, 64-row tile) ----------------
__global__ __launch_bounds__(256) void k_node1(const float* __restrict__ X,
                                               const float* __restrict__ W,
                                               float* __restrict__ Y, int nrows)
{
    __shared__ alignas(16) __bf16 sx[64 * 136];
    const int tid  = threadIdx.x;
    const int wv   = tid >> 6, lane = tid & 63;
    const int col  = lane & 15, quad = lane >> 4;

    bf16x8 wf[2][4];
    #pragma unroll
    for (int nt = 0; nt < 2; ++nt) {
        int n = wv * 32 + nt * 16 + col;
        #pragma unroll
        for (int kc = 0; kc < 4; ++kc)
            #pragma unroll
            for (int j = 0; j < 8; ++j)
                wf[nt][kc][j] = (__bf16)W[(kc * 32 + quad * 8 + j) * NF + n];
    }

    const int rbase = blockIdx.x * 64;
    for (int i = tid; i < 64 * 64; i += 256) {
        int r = i >> 6, c = i & 63;
        int gr = rbase + r;
        float2 v = (gr < nrows) ? *reinterpret_cast<const float2*>(&X[(size_t)gr * NF + 2 * c])
                                : make_float2(0.f, 0.f);
        sx[r * 136 + 2 * c]     = (__bf16)v.x;
        sx[r * 136 + 2 * c + 1] = (__bf16)v.y;
    }
    __syncthreads();

    f32x4 acc[4][2] = {};
    #pragma unroll
    for (int kc = 0; kc < 4; ++kc) {
        bf16x8 af[4];
        #pragma unroll
        for (int mt = 0; mt < 4; ++mt)
            af[mt] = *reinterpret_cast<const bf16x8*>(&sx[(mt * 16 + col) * 136 + kc * 32 + quad * 8]);
        #pragma unroll
        for (int mt = 0; mt < 4; ++mt)
            #pragma unroll
            for (int nt = 0; nt < 2; ++nt)
                acc[mt][nt] = __builtin_amdgcn_mfma_f32_16x16x32_bf16(af[mt], wf[nt][kc], acc[mt][nt], 0, 0, 0);
    }
    #pragma unroll
    for (int mt = 0; mt < 4; ++mt)
        #pragma unroll
        for (int nt = 0; nt < 2; ++nt)
            #pragma unroll
            for (int r = 0; r < 4; ++r) {
                int row = rbase + mt * 16 + quad * 4 + r;
                if (row < nrows) Y[(size_t)row * NF + wv * 32 + nt * 16 + col] = acc[mt][nt][r];
            }
}

// ---------------- fused tail: out = ssp(X @ W1 + b1) @ W2 + b2 ----------------
__global__ __launch_bounds__(256) void k_tail(const float* __restrict__ X,
                                              const float* __restrict__ W1, const float* __restrict__ B1,
                                              const float* __restrict__ W2, const float* __restrict__ B2,
                                              float* __restrict__ Y, int nrows)
{
    __shared__ alignas(16) __bf16 sx[64 * 136];
    __shared__ alignas(16) __bf16 st[64 * 136];
    const int tid  = threadIdx.x;
    const int wv   = tid >> 6, lane = tid & 63;
    const int col  = lane & 15, quad = lane >> 4;

    bf16x8 wf1[2][4], wf2[2][4];
    float rb1[2], rb2[2];
    #pragma unroll
    for (int nt = 0; nt < 2; ++nt) {
        int n = wv * 32 + nt * 16 + col;
        rb1[nt] = B1[n]; rb2[nt] = B2[n];
        #pragma unroll
        for (int kc = 0; kc < 4; ++kc)
            #pragma unroll
            for (int j = 0; j < 8; ++j) {
                int k = kc * 32 + quad * 8 + j;
                wf1[nt][kc][j] = (__bf16)W1[k * NF + n];
                wf2[nt][kc][j] = (__bf16)W2[k * NF + n];
            }
    }

    const int rbase = blockIdx.x * 64;
    for (int i = tid; i < 64 * 64; i += 256) {
        int r = i >> 6, c = i & 63;
        int gr = rbase + r;
        float2 v = (gr < nrows) ? *reinterpret_cast<const float2*>(&X[(size_t)gr * NF + 2 * c])
                                : make_float2(0.f, 0.f);
        sx[r * 136 + 2 * c]     = (__bf16)v.x;
        sx[r * 136 + 2 * c + 1] = (__bf16)v.y;
    }
    __syncthreads();

    f32x4 acc[4][2];
    #pragma unroll
    for (int mt = 0; mt < 4; ++mt)
        #pragma unroll
        for (int nt = 0; nt < 2; ++nt)
            acc[mt][nt] = f32x4{rb1[nt], rb1[nt], rb1[nt], rb1[nt]};
    #pragma unroll
    for (int kc = 0; kc < 4; ++kc) {
        bf16x8 af[4];
        #pragma unroll
        for (int mt = 0; mt < 4; ++mt)
            af[mt] = *reinterpret_cast<const bf16x8*>(&sx[(mt * 16 + col) * 136 + kc * 32 + quad * 8]);
        #pragma unroll
        for (int mt = 0; mt < 4; ++mt)
            #pragma unroll
            for (int nt = 0; nt < 2; ++nt)
                acc[mt][nt] = __builtin_amdgcn_mfma_f32_16x16x32_bf16(af[mt], wf1[nt][kc], acc[mt][nt], 0, 0, 0);
    }
    #pragma unroll
    for (int mt = 0; mt < 4; ++mt)
        #pragma unroll
        for (int nt = 0; nt < 2; ++nt)
            #pragma unroll
            for (int r = 0; r < 4; ++r)
                st[(mt * 16 + quad * 4 + r) * 136 + wv * 32 + nt * 16 + col] = (__bf16)ssp_f(acc[mt][nt][r]);
    __syncthreads();

    f32x4 acc2[4][2];
    #pragma unroll
    for (int mt = 0; mt < 4; ++mt)
        #pragma unroll
        for (int nt = 0; nt < 2; ++nt)
            acc2[mt][nt] = f32x4{rb2[nt], rb2[nt], rb2[nt], rb2[nt]};
    #pragma unroll
    for (int kc = 0; kc < 4; ++kc) {
        bf16x8 af[4];
        #pragma unroll
        for (int mt = 0; mt < 4; ++mt)
            af[mt] = *reinterpret_cast<const bf16x8*>(&st[(mt * 16 + col) * 136 + kc * 32 + quad * 8]);
        #pragma unroll
        for (int mt = 0; mt < 4; ++mt)
            #pragma unroll
            for (int nt = 0; nt < 2; ++nt)
                acc2[mt][nt] = __builtin_amdgcn_mfma_f32_16x16x32_bf16(af[mt], wf2[nt][kc], acc2[mt][nt], 0, 0, 0);
    }
    #pragma unroll
    for (int mt = 0; mt < 4; ++mt)
        #pragma unroll
        for (int nt = 0; nt < 2; ++nt)
            #pragma unroll
            for (int r = 0; r < 4; ++r) {
                int row = rbase + mt * 16 + quad * 4 + r;
                if (row < nrows) Y[(size_t)row * NF + wv * 32 + nt * 16 + col] = acc2[mt][nt][r];
            }
}

// ---------------- single-pass CSR edge kernel: MLP + gather + per-node reduce ----------------
// Round-0 body (LDS transpose, w1f/w2f in LDS, hoisted hg) + 3 additions:
//  * 1-tile-lookahead software pipeline: next tile's perm/srcs/Cs are loaded FIRST
//    (so the dependent ea-row loads only wait on them, not on the 32 hg loads -
//    vmcnt is FIFO), and next tile's 8 ea float2s are issued before the MLP so the
//    ~900-cycle HBM gather overlaps the ~1500-cycle MFMA/ssp chain. Prefetch is
//    unguarded (indices clamped; dead values are killed by Cw=0).
//  * s_setprio(1) around the MFMA clusters (independent waves per node).
//  * dynamic work-stealing over nodes, 512 persistent blocks = 2 blocks/CU.
// Register budget: ~200 (round-0) + ~32 prefetch state -> same 2-waves/SIMD tier
// (tier boundaries at 128/256). Spill tripwire: WRITE_SIZE must stay ~10.7 MB.
__global__ __launch_bounds__(256) void k_edge_csr(
    const int* __restrict__ off, const int* __restrict__ perm,
    const int* __restrict__ srcs, const float* __restrict__ Cs,
    const float* __restrict__ ea,
    const float* __restrict__ w1, const float* __restrict__ b1,
    const float* __restrict__ w2, const float* __restrict__ b2,
    const float* __restrict__ h, float* __restrict__ agg,
    int* __restrict__ wctr)
{
    __shared__ alignas(16) __bf16 w1f[16 * 64 * 8];   // 16 KB, frag = ntg*2+kc
    __shared__ alignas(16) __bf16 w2f[32 * 64 * 8];   // 32 KB, frag = ntg*4+kc
    __shared__ alignas(16) __bf16 st1[4][16 * 72];    // 9 KB, wave-private halves

    const int tid  = threadIdx.x;
    const int wv   = tid >> 6, lane = tid & 63;
    const int col  = lane & 15, quad = lane >> 4;

    // stage weight B-fragments (one-time)
    for (int idx = tid; idx < 16 * 64; idx += 256) {
        int fr = idx >> 6, l = idx & 63;
        int ntg = fr >> 1, kc = fr & 1;
        int n = ntg * 16 + (l & 15), kb = kc * 32 + (l >> 4) * 8;
        __bf16* d = &w1f[idx * 8];
        #pragma unroll
        for (int j = 0; j < 8; ++j) {
            int k = kb + j;
            d[j] = (__bf16)((k < NB) ? w1[k * NF + n] : 0.0f);
        }
    }
    for (int idx = tid; idx < 32 * 64; idx += 256) {
        int fr = idx >> 6, l = idx & 63;
        int ntg = fr >> 2, kc = fr & 3;
        int n = ntg * 16 + (l & 15), kb = kc * 32 + (l >> 4) * 8;
        __bf16* d = &w2f[idx * 8];
        #pragma unroll
        for (int j = 0; j < 8; ++j)
            d[j] = (__bf16)w2[(kb + j) * NF + n];
    }
    float rb1[8], rb2[8];
    #pragma unroll
    for (int nt = 0; nt < 8; ++nt) { rb1[nt] = b1[nt * 16 + col]; rb2[nt] = b2[nt * 16 + col]; }
    __syncthreads();   // the only barrier

    __bf16* myst = st1[wv];

    for (;;) {
        int n;
        if (lane == 0) n = atomicAdd(wctr, 1);
        n = __shfl(n, 0, 64);
        if (n >= NNODES) break;

        const int s = off[n], eend = off[n + 1];

        float pacc[8] = {0.f, 0.f, 0.f, 0.f, 0.f, 0.f, 0.f, 0.f};

        // ---- prologue: first tile's meta + raw ea row
        int pos  = s + col;
        int lpos = min(pos, NEDGES - 1);
        int eidc = perm[lpos];
        int srcc = srcs[lpos];
        float Cv = (pos < eend) ? Cs[lpos] : 0.0f;
        float2 ra[8];
        {
            const float* erow = ea + (size_t)eidc * NB;
            #pragma unroll
            for (int p = 0; p < 4; ++p)
                ra[p] = *reinterpret_cast<const float2*>(erow + quad * 8 + 2 * p);
            #pragma unroll
            for (int p = 0; p < 4; ++p) {
                int k = 32 + quad * 8 + 2 * p;
                ra[4 + p] = (k + 2 <= NB) ? *reinterpret_cast<const float2*>(erow + k)
                                          : make_float2(0.f, 0.f);
            }
        }

        for (int base = s; base < eend; base += 16) {
            // per-row (quad*4+r) metadata via cross-lane pull (current tile)
            int   src_r[4];
            float Cw[4];
            #pragma unroll
            for (int r = 0; r < 4; ++r) {
                int sl = quad * 4 + r;
                src_r[r] = __shfl(srcc, sl, 64);
                Cw[r]    = __shfl(Cv,   sl, 64);
            }

            // ---- prefetch NEXT tile's meta FIRST (so ea-prefetch waits only on these)
            int npos  = base + 16 + col;
            int nlpos = min(npos, NEDGES - 1);
            int neid  = perm[nlpos];
            int nsrc  = srcs[nlpos];
            float nCv = (npos < eend) ? Cs[nlpos] : 0.0f;

            // hoisted hg gathers (hide behind the MLP; issued after meta loads)
            float hg[8][4];
            #pragma unroll
            for (int nt = 0; nt < 8; ++nt)
                #pragma unroll
                for (int r = 0; r < 4; ++r)
                    hg[nt][r] = h[(size_t)src_r[r] * NF + nt * 16 + col];

            // convert this tile's raw floats (already in regs) to A-frags
            bf16x8 af0, af1;
            #pragma unroll
            for (int p = 0; p < 4; ++p) {
                af0[2 * p]     = (__bf16)ra[p].x;
                af0[2 * p + 1] = (__bf16)ra[p].y;
                af1[2 * p]     = (__bf16)ra[4 + p].x;
                af1[2 * p + 1] = (__bf16)ra[4 + p].y;
            }

            // ---- issue NEXT tile's raw ea loads (overlaps the MLP below)
            float2 nra[8];
            {
                const float* nerow = ea + (size_t)neid * NB;
                #pragma unroll
                for (int p = 0; p < 4; ++p)
                    nra[p] = *reinterpret_cast<const float2*>(nerow + quad * 8 + 2 * p);
                #pragma unroll
                for (int p = 0; p < 4; ++p) {
                    int k = 32 + quad * 8 + 2 * p;
                    nra[4 + p] = (k + 2 <= NB) ? *reinterpret_cast<const float2*>(nerow + k)
                                               : make_float2(0.f, 0.f);
                }
            }

            f32x4 acc2[8];
            #pragma unroll
            for (int nt = 0; nt < 8; ++nt) acc2[nt] = f32x4{rb2[nt], rb2[nt], rb2[nt], rb2[nt]};

            #pragma unroll
            for (int hf = 0; hf < 2; ++hf) {
                f32x4 acc1[4];
                __builtin_amdgcn_s_setprio(1);
                #pragma unroll
                for (int nt = 0; nt < 4; ++nt) {
                    int ntg = hf * 4 + nt;
                    acc1[nt] = f32x4{rb1[ntg], rb1[ntg], rb1[ntg], rb1[ntg]};
                    bf16x8 bw0 = *reinterpret_cast<const bf16x8*>(&w1f[((ntg * 2 + 0) * 64 + lane) * 8]);
                    bf16x8 bw1 = *reinterpret_cast<const bf16x8*>(&w1f[((ntg * 2 + 1) * 64 + lane) * 8]);
                    acc1[nt] = __builtin_amdgcn_mfma_f32_16x16x32_bf16(af0, bw0, acc1[nt], 0, 0, 0);
                    acc1[nt] = __builtin_amdgcn_mfma_f32_16x16x32_bf16(af1, bw1, acc1[nt], 0, 0, 0);
                }
                __builtin_amdgcn_s_setprio(0);
                #pragma unroll
                for (int nt = 0; nt < 4; ++nt)
                    #pragma unroll
                    for (int r = 0; r < 4; ++r)
                        myst[(quad * 4 + r) * 72 + nt * 16 + col] = (__bf16)ssp_f(acc1[nt][r]);
                bf16x8 a20 = *reinterpret_cast<const bf16x8*>(&myst[col * 72 + 0 * 32 + quad * 8]);
                bf16x8 a21 = *reinterpret_cast<const bf16x8*>(&myst[col * 72 + 1 * 32 + quad * 8]);
                __builtin_amdgcn_s_setprio(1);
                #pragma unroll
                for (int nt = 0; nt < 8; ++nt) {
                    bf16x8 b20 = *reinterpret_cast<const bf16x8*>(&w2f[((nt * 4 + hf * 2 + 0) * 64 + lane) * 8]);
                    bf16x8 b21 = *reinterpret_cast<const bf16x8*>(&w2f[((nt * 4 + hf * 2 + 1) * 64 + lane) * 8]);
                    acc2[nt] = __builtin_amdgcn_mfma_f32_16x16x32_bf16(a20, b20, acc2[nt], 0, 0, 0);
                    acc2[nt] = __builtin_amdgcn_mfma_f32_16x16x32_bf16(a21, b21, acc2[nt], 0, 0, 0);
                }
                __builtin_amdgcn_s_setprio(0);
            }

            // accumulate this tile's contribution (padded rows have Cw=0)
            #pragma unroll
            for (int nt = 0; nt < 8; ++nt)
                #pragma unroll
                for (int r = 0; r < 4; ++r) {
                    float t = Cw[r] * hg[nt][r];
                    pacc[nt] = fmaf(acc2[nt][r], t, pacc[nt]);
                }

            // rotate pipeline state
            srcc = nsrc; Cv = nCv;
            #pragma unroll
            for (int i = 0; i < 8; ++i) ra[i] = nra[i];
        }

        // cross-quad reduce (sum the 4 row-groups) and write the agg row
        #pragma unroll
        for (int nt = 0; nt < 8; ++nt) {
            float v = pacc[nt];
            v += __shfl_xor(v, 16, 64);
            v += __shfl_xor(v, 32, 64);
            if (lane < 16) agg[(size_t)n * NF + nt * 16 + lane] = v;
        }
    }
}

extern "C" void kernel_launch(void* const* d_in, const int* in_sizes, int n_in,
                              void* d_out, int out_size, void* d_ws, size_t ws_size,
                              hipStream_t stream) {
    const float* x    = (const float*)d_in[0];
    const int*   eidx = (const int*)d_in[1];
    const float* ew   = (const float*)d_in[2];
    const float* ea   = (const float*)d_in[3];
    const float* w1   = (const float*)d_in[4];
    const float* b1   = (const float*)d_in[5];
    const float* w2   = (const float*)d_in[6];
    const float* b2   = (const float*)d_in[7];
    const float* l1w  = (const float*)d_in[8];
    const float* l2w  = (const float*)d_in[9];
    const float* l2b  = (const float*)d_in[10];
    const float* lw   = (const float*)d_in[11];
    const float* lb   = (const float*)d_in[12];
    (void)in_sizes; (void)n_in; (void)out_size; (void)ws_size;

    const int* esrc = eidx;
    const int* edst = eidx + NEDGES;

    char* p = (char*)d_ws;
    float*  h    = (float*)p;  p += (size_t)NNODES * NF * 4;      // 10.24 MB
    float*  agg  = (float*)p;  p += (size_t)NNODES * NF * 4;      // 10.24 MB
    int*    off  = (int*)p;    p += (size_t)(NNODES + 4) * 4;
    int*    hist = (int*)p;    p += (size_t)NNODES * 4;
    int*    cnt  = (int*)p;    p += (size_t)NNODES * 4;
    int*    wctr = (int*)p;    p += 64 * 4;                       // work-steal counter (zeroed with hist/cnt)
    int*    bsum = (int*)p;    p += 128 * 4;
    int*    bbase= (int*)p;    p += 128 * 4;
    int*    perm = (int*)p;    p += (size_t)NEDGES * 4;           // 2.56 MB
    int*    srcs = (int*)p;    p += (size_t)NEDGES * 4;           // 2.56 MB
    float*  Cs   = (float*)p;  p += (size_t)NEDGES * 4;           // 2.56 MB

    // h = x @ lin1_w (MFMA)
    hipLaunchKernelGGL(k_node1, dim3(313), dim3(256), 0, stream, x, l1w, h, NNODES);

    // dst-sorted CSR build (hist -> hierarchical scan -> scatter w/ pre-gather)
    // zero range covers hist + cnt + wctr (contiguous)
    hipLaunchKernelGGL(k_zero_small, dim3(157), dim3(256), 0, stream, hist, 2 * NNODES + 64);
    hipLaunchKernelGGL(k_hist, dim3(2500), dim3(256), 0, stream, edst, hist);
    hipLaunchKernelGGL(k_bsum, dim3(NBLK_SCAN), dim3(256), 0, stream, hist, bsum);
    hipLaunchKernelGGL(k_scan_b, dim3(1), dim3(64), 0, stream, bsum, bbase);
    hipLaunchKernelGGL(k_off, dim3(NBLK_SCAN), dim3(256), 0, stream, hist, bbase, off);
    hipLaunchKernelGGL(k_scatter, dim3(2500), dim3(256), 0, stream,
                       esrc, edst, ew, off, cnt, perm, srcs, Cs);

    // single-pass fused edge MLP + CFConv + per-node reduce (pipelined, work-stealing)
    hipLaunchKernelGGL(k_edge_csr, dim3(512), dim3(256), 0, stream,
                       off, perm, srcs, Cs, ea, w1, b1, w2, b2, h, agg, wctr);

    // out = ssp(agg @ lin2_w + lin2_b) @ lin_w + lin_b (fused MFMA)
    hipLaunchKernelGGL(k_tail, dim3(313), dim3(256), 0, stream,
                       agg, l2w, l2b, lw, lb, (float*)d_out, NNODES);
}

// Round 8
// 577.992 us; speedup vs baseline: 1.6354x; 1.0070x over previous
//
#include <hip/hip_runtime.h>
#include <hip/hip_bf16.h>

#define NNODES 20000
#define NEDGES 640000
#define NB 50
#define NF 128
#define NBLK_SCAN 79   // ceil(20000/256)

typedef unsigned int uint_t;
typedef unsigned short ushort_t;

typedef __bf16 bf16x8 __attribute__((ext_vector_type(8)));
typedef float f32x4 __attribute__((ext_vector_type(4)));

// fast shifted softplus: hardware v_exp_f32 / v_log_f32
__device__ __forceinline__ float ssp_f(float x) {
    float t = __expf(-fabsf(x));
    return fmaxf(x, 0.0f) + __logf(1.0f + t) - 0.6931471805599453f;
}

// ---------------- zero hist + cnt + work counter ----------------
__global__ __launch_bounds__(256) void k_zero_small(int* __restrict__ p, int n) {
    int i = blockIdx.x * 256 + threadIdx.x;
    if (i < n) p[i] = 0;
}

// ---------------- histogram of dst ----------------
__global__ __launch_bounds__(256) void k_hist(const int* __restrict__ dst, int* __restrict__ hist) {
    int i = blockIdx.x * 256 + threadIdx.x;
    if (i < NEDGES) atomicAdd(&hist[dst[i]], 1);
}

// ---------------- hierarchical exclusive scan: blocksums ----------------
__global__ __launch_bounds__(256) void k_bsum(const int* __restrict__ hist, int* __restrict__ bsum) {
    __shared__ int ws[4];
    int i = blockIdx.x * 256 + threadIdx.x;
    int v = (i < NNODES) ? hist[i] : 0;
    #pragma unroll
    for (int s = 1; s < 64; s <<= 1) v += __shfl_xor(v, s, 64);
    if ((threadIdx.x & 63) == 0) ws[threadIdx.x >> 6] = v;
    __syncthreads();
    if (threadIdx.x == 0) bsum[blockIdx.x] = ws[0] + ws[1] + ws[2] + ws[3];
}

__global__ __launch_bounds__(64) void k_scan_b(const int* __restrict__ bsum, int* __restrict__ bbase) {
    if (threadIdx.x == 0) {
        int acc = 0;
        for (int b = 0; b < NBLK_SCAN; ++b) { bbase[b] = acc; acc += bsum[b]; }
    }
}

__global__ __launch_bounds__(256) void k_off(const int* __restrict__ hist, const int* __restrict__ bbase,
                                             int* __restrict__ off) {
    __shared__ int buf[256];
    int i = blockIdx.x * 256 + threadIdx.x;
    int v = (i < NNODES) ? hist[i] : 0;
    buf[threadIdx.x] = v;
    __syncthreads();
    #pragma unroll
    for (int s = 1; s < 256; s <<= 1) {
        int t = (threadIdx.x >= (unsigned)s) ? buf[threadIdx.x - s] : 0;
        __syncthreads();
        buf[threadIdx.x] += t;
        __syncthreads();
    }
    if (i < NNODES) off[i] = bbase[blockIdx.x] + buf[threadIdx.x] - v;
    if (i == NNODES) off[NNODES] = NEDGES;
}

// ---------------- scatter: dst-grouped perm + pre-gathered src + cutoff ----------------
__global__ __launch_bounds__(256) void k_scatter(const int* __restrict__ src, const int* __restrict__ dst,
                                                 const float* __restrict__ ew,
                                                 const int* __restrict__ off, int* __restrict__ cnt,
                                                 int* __restrict__ perm, int* __restrict__ srcs,
                                                 float* __restrict__ Cs) {
    int i = blockIdx.x * 256 + threadIdx.x;
    if (i < NEDGES) {
        int d = dst[i];
        int pos = off[d] + atomicAdd(&cnt[d], 1);
        perm[pos] = i;
        srcs[pos] = src[i];
        Cs[pos]   = 0.5f * (__cosf(ew[i] * 0.31415926535897931f) + 1.0f);
    }
}

// ---------------- node GEMM: Y = X @ W  (MFMA, 64-row tile) ----------------
__global__ __launch_bounds__(256) void k_node1(const float* __restrict__ X,
                                               const float* __restrict__ W,
                                               float* __restrict__ Y, int nrows)
{
    __shared__ alignas(16) __bf16 sx[64 * 136];
    const int tid  = threadIdx.x;
    const int wv   = tid >> 6, lane = tid & 63;
    const int col  = lane & 15, quad = lane >> 4;

    bf16x8 wf[2][4];
    #pragma unroll
    for (int nt = 0; nt < 2; ++nt) {
        int n = wv * 32 + nt * 16 + col;
        #pragma unroll
        for (int kc = 0; kc < 4; ++kc)
            #pragma unroll
            for (int j = 0; j < 8; ++j)
                wf[nt][kc][j] = (__bf16)W[(kc * 32 + quad * 8 + j) * NF + n];
    }

    const int rbase = blockIdx.x * 64;
    for (int i = tid; i < 64 * 64; i += 256) {
        int r = i >> 6, c = i & 63;
        int gr = rbase + r;
        float2 v = (gr < nrows) ? *reinterpret_cast<const float2*>(&X[(size_t)gr * NF + 2 * c])
                                : make_float2(0.f, 0.f);
        sx[r * 136 + 2 * c]     = (__bf16)v.x;
        sx[r * 136 + 2 * c + 1] = (__bf16)v.y;
    }
    __syncthreads();

    f32x4 acc[4][2] = {};
    #pragma unroll
    for (int kc = 0; kc < 4; ++kc) {
        bf16x8 af[4];
        #pragma unroll
        for (int mt = 0; mt < 4; ++mt)
            af[mt] = *reinterpret_cast<const bf16x8*>(&sx[(mt * 16 + col) * 136 + kc * 32 + quad * 8]);
        #pragma unroll
        for (int mt = 0; mt < 4; ++mt)
            #pragma unroll
            for (int nt = 0; nt < 2; ++nt)
                acc[mt][nt] = __builtin_amdgcn_mfma_f32_16x16x32_bf16(af[mt], wf[nt][kc], acc[mt][nt], 0, 0, 0);
    }
    #pragma unroll
    for (int mt = 0; mt < 4; ++mt)
        #pragma unroll
        for (int nt = 0; nt < 2; ++nt)
            #pragma unroll
            for (int r = 0; r < 4; ++r) {
                int row = rbase + mt * 16 + quad * 4 + r;
                if (row < nrows) Y[(size_t)row * NF + wv * 32 + nt * 16 + col] = acc[mt][nt][r];
            }
}

// ---------------- fused tail: out = ssp(X @ W1 + b1) @ W2 + b2 ----------------
__global__ __launch_bounds__(256) void k_tail(const float* __restrict__ X,
                                              const float* __restrict__ W1, const float* __restrict__ B1,
                                              const float* __restrict__ W2, const float* __restrict__ B2,
                                              float* __restrict__ Y, int nrows)
{
    __shared__ alignas(16) __bf16 sx[64 * 136];
    __shared__ alignas(16) __bf16 st[64 * 136];
    const int tid  = threadIdx.x;
    const int wv   = tid >> 6, lane = tid & 63;
    const int col  = lane & 15, quad = lane >> 4;

    bf16x8 wf1[2][4], wf2[2][4];
    float rb1[2], rb2[2];
    #pragma unroll
    for (int nt = 0; nt < 2; ++nt) {
        int n = wv * 32 + nt * 16 + col;
        rb1[nt] = B1[n]; rb2[nt] = B2[n];
        #pragma unroll
        for (int kc = 0; kc < 4; ++kc)
            #pragma unroll
            for (int j = 0; j < 8; ++j) {
                int k = kc * 32 + quad * 8 + j;
                wf1[nt][kc][j] = (__bf16)W1[k * NF + n];
                wf2[nt][kc][j] = (__bf16)W2[k * NF + n];
            }
    }

    const int rbase = blockIdx.x * 64;
    for (int i = tid; i < 64 * 64; i += 256) {
        int r = i >> 6, c = i & 63;
        int gr = rbase + r;
        float2 v = (gr < nrows) ? *reinterpret_cast<const float2*>(&X[(size_t)gr * NF + 2 * c])
                                : make_float2(0.f, 0.f);
        sx[r * 136 + 2 * c]     = (__bf16)v.x;
        sx[r * 136 + 2 * c + 1] = (__bf16)v.y;
    }
    __syncthreads();

    f32x4 acc[4][2];
    #pragma unroll
    for (int mt = 0; mt < 4; ++mt)
        #pragma unroll
        for (int nt = 0; nt < 2; ++nt)
            acc[mt][nt] = f32x4{rb1[nt], rb1[nt], rb1[nt], rb1[nt]};
    #pragma unroll
    for (int kc = 0; kc < 4; ++kc) {
        bf16x8 af[4];
        #pragma unroll
        for (int mt = 0; mt < 4; ++mt)
            af[mt] = *reinterpret_cast<const bf16x8*>(&sx[(mt * 16 + col) * 136 + kc * 32 + quad * 8]);
        #pragma unroll
        for (int mt = 0; mt < 4; ++mt)
            #pragma unroll
            for (int nt = 0; nt < 2; ++nt)
                acc[mt][nt] = __builtin_amdgcn_mfma_f32_16x16x32_bf16(af[mt], wf1[nt][kc], acc[mt][nt], 0, 0, 0);
    }
    #pragma unroll
    for (int mt = 0; mt < 4; ++mt)
        #pragma unroll
        for (int nt = 0; nt < 2; ++nt)
            #pragma unroll
            for (int r = 0; r < 4; ++r)
                st[(mt * 16 + quad * 4 + r) * 136 + wv * 32 + nt * 16 + col] = (__bf16)ssp_f(acc[mt][nt][r]);
    __syncthreads();

    f32x4 acc2[4][2];
    #pragma unroll
    for (int mt = 0; mt < 4; ++mt)
        #pragma unroll
        for (int nt = 0; nt < 2; ++nt)
            acc2[mt][nt] = f32x4{rb2[nt], rb2[nt], rb2[nt], rb2[nt]};
    #pragma unroll
    for (int kc = 0; kc < 4; ++kc) {
        bf16x8 af[4];
        #pragma unroll
        for (int mt = 0; mt < 4; ++mt)
            af[mt] = *reinterpret_cast<const bf16x8*>(&st[(mt * 16 + col) * 136 + kc * 32 + quad * 8]);
        #pragma unroll
        for (int mt = 0; mt < 4; ++mt)
            #pragma unroll
            for (int nt = 0; nt < 2; ++nt)
                acc2[mt][nt] = __builtin_amdgcn_mfma_f32_16x16x32_bf16(af[mt], wf2[nt][kc], acc2[mt][nt], 0, 0, 0);
    }
    #pragma unroll
    for (int mt = 0; mt < 4; ++mt)
        #pragma unroll
        for (int nt = 0; nt < 2; ++nt)
            #pragma unroll
            for (int r = 0; r < 4; ++r) {
                int row = rbase + mt * 16 + quad * 4 + r;
                if (row < nrows) Y[(size_t)row * NF + wv * 32 + nt * 16 + col] = acc2[mt][nt][r];
            }
}

// ---------------- single-pass CSR edge kernel: MLP + gather + per-node reduce ----------------
// Round-0 body with exactly two zero-cost changes:
//  * VMEM ISSUE ORDER: meta trio (perm/srcs/Cs) first, then the 8 ea-row loads,
//    THEN the shfl-dependent 32 hg gathers. vmcnt is FIFO, so the L1 MFMA's wait
//    on ea now leaves the 32 hg gathers outstanding (vmcnt(32)) instead of
//    draining the whole queue; hg drains under the ~800-cycle MLP and is only
//    consumed by the final pacc fma. Round-0 issued hg BEFORE ea, forcing the
//    first MFMA to wait on the entire 40-load clause.
//  * dynamic work-stealing over nodes (512 persistent blocks = 2/CU): removes
//    the 1000-block/512-slot two-round quantization and the degree tail.
// No new instructions in the loop body, no prefetch (R7 lesson), no extra state.
__global__ __launch_bounds__(256) void k_edge_csr(
    const int* __restrict__ off, const int* __restrict__ perm,
    const int* __restrict__ srcs, const float* __restrict__ Cs,
    const float* __restrict__ ea,
    const float* __restrict__ w1, const float* __restrict__ b1,
    const float* __restrict__ w2, const float* __restrict__ b2,
    const float* __restrict__ h, float* __restrict__ agg,
    int* __restrict__ wctr)
{
    __shared__ alignas(16) __bf16 w1f[16 * 64 * 8];   // 16 KB, frag = ntg*2+kc
    __shared__ alignas(16) __bf16 w2f[32 * 64 * 8];   // 32 KB, frag = ntg*4+kc
    __shared__ alignas(16) __bf16 st1[4][16 * 72];    // 9 KB, wave-private halves

    const int tid  = threadIdx.x;
    const int wv   = tid >> 6, lane = tid & 63;
    const int col  = lane & 15, quad = lane >> 4;

    // stage weight B-fragments (one-time)
    for (int idx = tid; idx < 16 * 64; idx += 256) {
        int fr = idx >> 6, l = idx & 63;
        int ntg = fr >> 1, kc = fr & 1;
        int n = ntg * 16 + (l & 15), kb = kc * 32 + (l >> 4) * 8;
        __bf16* d = &w1f[idx * 8];
        #pragma unroll
        for (int j = 0; j < 8; ++j) {
            int k = kb + j;
            d[j] = (__bf16)((k < NB) ? w1[k * NF + n] : 0.0f);
        }
    }
    for (int idx = tid; idx < 32 * 64; idx += 256) {
        int fr = idx >> 6, l = idx & 63;
        int ntg = fr >> 2, kc = fr & 3;
        int n = ntg * 16 + (l & 15), kb = kc * 32 + (l >> 4) * 8;
        __bf16* d = &w2f[idx * 8];
        #pragma unroll
        for (int j = 0; j < 8; ++j)
            d[j] = (__bf16)w2[(kb + j) * NF + n];
    }
    float rb1[8], rb2[8];
    #pragma unroll
    for (int nt = 0; nt < 8; ++nt) { rb1[nt] = b1[nt * 16 + col]; rb2[nt] = b2[nt * 16 + col]; }
    __syncthreads();   // the only barrier

    __bf16* myst = st1[wv];

    for (;;) {
        int n;
        if (lane == 0) n = atomicAdd(wctr, 1);
        n = __shfl(n, 0, 64);
        if (n >= NNODES) break;

        const int s = off[n], eend = off[n + 1];

        float pacc[8] = {0.f, 0.f, 0.f, 0.f, 0.f, 0.f, 0.f, 0.f};

        for (int base = s; base < eend; base += 16) {
            // per-lane slot (col dimension); lanes 16-63 duplicate cols 0-15
            int pos  = base + col;
            int lpos = min(pos, NEDGES - 1);
            // ---- meta trio first
            int eidc = perm[lpos];
            int srcc = srcs[lpos];
            float Cv = (pos < eend) ? Cs[lpos] : 0.0f;

            // ---- ea row loads IMMEDIATELY (depend only on eidc; issued before
            //      the hg gathers so the L1 MFMA's vmcnt wait excludes them)
            const float* erow = ea + (size_t)eidc * NB;
            float2 ra[8];
            #pragma unroll
            for (int p = 0; p < 4; ++p)
                ra[p] = *reinterpret_cast<const float2*>(erow + quad * 8 + 2 * p);
            #pragma unroll
            for (int p = 0; p < 4; ++p) {
                int k = 32 + quad * 8 + 2 * p;
                ra[4 + p] = (k + 2 <= NB) ? *reinterpret_cast<const float2*>(erow + k)
                                          : make_float2(0.f, 0.f);
            }

            // per-row (quad*4+r) metadata via cross-lane pull
            int   src_r[4];
            float Cw[4];
            #pragma unroll
            for (int r = 0; r < 4; ++r) {
                int sl = quad * 4 + r;
                src_r[r] = __shfl(srcc, sl, 64);
                Cw[r]    = __shfl(Cv,   sl, 64);
            }

            // ---- hg gathers LAST (drain under the MLP; consumed only by pacc)
            float hg[8][4];
            #pragma unroll
            for (int nt = 0; nt < 8; ++nt)
                #pragma unroll
                for (int r = 0; r < 4; ++r)
                    hg[nt][r] = h[(size_t)src_r[r] * NF + nt * 16 + col];

            // convert ea floats to A-frags
            bf16x8 af0, af1;
            #pragma unroll
            for (int p = 0; p < 4; ++p) {
                af0[2 * p]     = (__bf16)ra[p].x;
                af0[2 * p + 1] = (__bf16)ra[p].y;
                af1[2 * p]     = (__bf16)ra[4 + p].x;
                af1[2 * p + 1] = (__bf16)ra[4 + p].y;
            }

            f32x4 acc2[8];
            #pragma unroll
            for (int nt = 0; nt < 8; ++nt) acc2[nt] = f32x4{rb2[nt], rb2[nt], rb2[nt], rb2[nt]};

            #pragma unroll
            for (int hf = 0; hf < 2; ++hf) {
                f32x4 acc1[4];
                #pragma unroll
                for (int nt = 0; nt < 4; ++nt) {
                    int ntg = hf * 4 + nt;
                    acc1[nt] = f32x4{rb1[ntg], rb1[ntg], rb1[ntg], rb1[ntg]};
                    bf16x8 bw0 = *reinterpret_cast<const bf16x8*>(&w1f[((ntg * 2 + 0) * 64 + lane) * 8]);
                    bf16x8 bw1 = *reinterpret_cast<const bf16x8*>(&w1f[((ntg * 2 + 1) * 64 + lane) * 8]);
                    acc1[nt] = __builtin_amdgcn_mfma_f32_16x16x32_bf16(af0, bw0, acc1[nt], 0, 0, 0);
                    acc1[nt] = __builtin_amdgcn_mfma_f32_16x16x32_bf16(af1, bw1, acc1[nt], 0, 0, 0);
                }
                #pragma unroll
                for (int nt = 0; nt < 4; ++nt)
                    #pragma unroll
                    for (int r = 0; r < 4; ++r)
                        myst[(quad * 4 + r) * 72 + nt * 16 + col] = (__bf16)ssp_f(acc1[nt][r]);
                bf16x8 a20 = *reinterpret_cast<const bf16x8*>(&myst[col * 72 + 0 * 32 + quad * 8]);
                bf16x8 a21 = *reinterpret_cast<const bf16x8*>(&myst[col * 72 + 1 * 32 + quad * 8]);
                #pragma unroll
                for (int nt = 0; nt < 8; ++nt) {
                    bf16x8 b20 = *reinterpret_cast<const bf16x8*>(&w2f[((nt * 4 + hf * 2 + 0) * 64 + lane) * 8]);
                    bf16x8 b21 = *reinterpret_cast<const bf16x8*>(&w2f[((nt * 4 + hf * 2 + 1) * 64 + lane) * 8]);
                    acc2[nt] = __builtin_amdgcn_mfma_f32_16x16x32_bf16(a20, b20, acc2[nt], 0, 0, 0);
                    acc2[nt] = __builtin_amdgcn_mfma_f32_16x16x32_bf16(a21, b21, acc2[nt], 0, 0, 0);
                }
            }

            // accumulate this tile's contribution (padded rows have Cw=0)
            #pragma unroll
            for (int nt = 0; nt < 8; ++nt)
                #pragma unroll
                for (int r = 0; r < 4; ++r) {
                    float t = Cw[r] * hg[nt][r];
                    pacc[nt] = fmaf(acc2[nt][r], t, pacc[nt]);
                }
        }

        // cross-quad reduce (sum the 4 row-groups) and write the agg row
        #pragma unroll
        for (int nt = 0; nt < 8; ++nt) {
            float v = pacc[nt];
            v += __shfl_xor(v, 16, 64);
            v += __shfl_xor(v, 32, 64);
            if (lane < 16) agg[(size_t)n * NF + nt * 16 + lane] = v;
        }
    }
}

extern "C" void kernel_launch(void* const* d_in, const int* in_sizes, int n_in,
                              void* d_out, int out_size, void* d_ws, size_t ws_size,
                              hipStream_t stream) {
    const float* x    = (const float*)d_in[0];
    const int*   eidx = (const int*)d_in[1];
    const float* ew   = (const float*)d_in[2];
    const float* ea   = (const float*)d_in[3];
    const float* w1   = (const float*)d_in[4];
    const float* b1   = (const float*)d_in[5];
    const float* w2   = (const float*)d_in[6];
    const float* b2   = (const float*)d_in[7];
    const float* l1w  = (const float*)d_in[8];
    const float* l2w  = (const float*)d_in[9];
    const float* l2b  = (const float*)d_in[10];
    const float* lw   = (const float*)d_in[11];
    const float* lb   = (const float*)d_in[12];
    (void)in_sizes; (void)n_in; (void)out_size; (void)ws_size;

    const int* esrc = eidx;
    const int* edst = eidx + NEDGES;

    char* p = (char*)d_ws;
    float*  h    = (float*)p;  p += (size_t)NNODES * NF * 4;      // 10.24 MB
    float*  agg  = (float*)p;  p += (size_t)NNODES * NF * 4;      // 10.24 MB
    int*    off  = (int*)p;    p += (size_t)(NNODES + 4) * 4;
    int*    hist = (int*)p;    p += (size_t)NNODES * 4;
    int*    cnt  = (int*)p;    p += (size_t)NNODES * 4;
    int*    wctr = (int*)p;    p += 64 * 4;                       // work-steal counter (zeroed with hist/cnt)
    int*    bsum = (int*)p;    p += 128 * 4;
    int*    bbase= (int*)p;    p += 128 * 4;
    int*    perm = (int*)p;    p += (size_t)NEDGES * 4;           // 2.56 MB
    int*    srcs = (int*)p;    p += (size_t)NEDGES * 4;           // 2.56 MB
    float*  Cs   = (float*)p;  p += (size_t)NEDGES * 4;           // 2.56 MB

    // h = x @ lin1_w (MFMA)
    hipLaunchKernelGGL(k_node1, dim3(313), dim3(256), 0, stream, x, l1w, h, NNODES);

    // dst-sorted CSR build (hist -> hierarchical scan -> scatter w/ pre-gather)
    // zero range covers hist + cnt + wctr (contiguous)
    hipLaunchKernelGGL(k_zero_small, dim3(157), dim3(256), 0, stream, hist, 2 * NNODES + 64);
    hipLaunchKernelGGL(k_hist, dim3(2500), dim3(256), 0, stream, edst, hist);
    hipLaunchKernelGGL(k_bsum, dim3(NBLK_SCAN), dim3(256), 0, stream, hist, bsum);
    hipLaunchKernelGGL(k_scan_b, dim3(1), dim3(64), 0, stream, bsum, bbase);
    hipLaunchKernelGGL(k_off, dim3(NBLK_SCAN), dim3(256), 0, stream, hist, bbase, off);
    hipLaunchKernelGGL(k_scatter, dim3(2500), dim3(256), 0, stream,
                       esrc, edst, ew, off, cnt, perm, srcs, Cs);

    // single-pass fused edge MLP + CFConv + per-node reduce (reordered VMEM, work-stealing)
    hipLaunchKernelGGL(k_edge_csr, dim3(512), dim3(256), 0, stream,
                       off, perm, srcs, Cs, ea, w1, b1, w2, b2, h, agg, wctr);

    // out = ssp(agg @ lin2_w + lin2_b) @ lin_w + lin_b (fused MFMA)
    hipLaunchKernelGGL(k_tail, dim3(313), dim3(256), 0, stream,
                       agg, l2w, l2b, lw, lb, (float*)d_out, NNODES);
}